// Round 3
// baseline (1904.152 us; speedup 1.0000x reference)
//
#include <hip/hip_runtime.h>
#include <hip/hip_bf16.h>
#include <math.h>

#define KCL 2048
#define LRELU_NEG 0.01f
#define EPSBN 1e-5f

using s8v = __attribute__((ext_vector_type(8))) short;   // 8 bf16 (4 VGPRs)
using f4v = __attribute__((ext_vector_type(4))) float;   // MFMA accumulator

union U8 { ushort u[8]; uint4 v; };

__device__ __forceinline__ float lrelu(float x) { return x > 0.f ? x : LRELU_NEG * x; }
__device__ __forceinline__ ushort f2bf(float f) {
    __hip_bfloat16 h = __float2bfloat16(f);
    return *reinterpret_cast<ushort*>(&h);
}
__device__ __forceinline__ float bf2f(ushort u) { return __uint_as_float(((unsigned)u) << 16); }

// monotonic float->uint encoding for atomicMax over mixed-sign floats
__device__ __forceinline__ unsigned encf(float f) {
    unsigned u = __float_as_uint(f);
    return (u & 0x80000000u) ? ~u : (u | 0x80000000u);
}
__device__ __forceinline__ float decf(unsigned u) {
    return __uint_as_float((u & 0x80000000u) ? (u & 0x7fffffffu) : ~u);
}

// finalize BN stats into LDS scale/bias: y = x*sb[col] + sb[64+col]
__device__ __forceinline__ void bn_sb(const double* __restrict__ stats, const float* __restrict__ g,
                                      const float* __restrict__ b, int n, float* sb) {
    int t = threadIdx.x;
    if (t < 64) {
        float mean = (float)(stats[t] / n);
        float ex2 = (float)(stats[64 + t] / n);
        float var = fmaxf(ex2 - mean * mean, 0.f);
        float rstd = rsqrtf(var + EPSBN);
        float sc = rstd * g[t];
        sb[t] = sc;
        sb[64 + t] = b[t] - mean * sc;
    }
    __syncthreads();
}

// ---------------- weight prep: 64 matrices of 64x64, transposed -> bf16 ----------------
__global__ __launch_bounds__(256) void prep_wt64(const float* __restrict__ lw, const float* __restrict__ wW,
                                                 const float* __restrict__ proj, const float* __restrict__ c1,
                                                 const float* __restrict__ c2, ushort* __restrict__ wt) {
    int bk = blockIdx.x;
    const float* W;
    if (bk < 3) W = lw + (size_t)bk * 4096;
    else if (bk < 6) W = wW + (size_t)(bk - 3) * 4096;
    else if (bk < 10) W = proj + (size_t)(bk - 6) * 4096;
    else if (bk < 37) W = c1 + (size_t)(bk - 10) * 4096;
    else W = c2 + (size_t)(bk - 37) * 4096;
    ushort* o = wt + (size_t)bk * 4096;
    for (int i = threadIdx.x; i < 4096; i += 256) {
        int kk = i >> 6, cc = i & 63;
        o[cc * 64 + kk] = f2bf(W[i]);
    }
}

__global__ __launch_bounds__(256) void prep_fuse(const float* __restrict__ Wf, ushort* __restrict__ o) {
    for (int i = threadIdx.x; i < 8192; i += 256) {
        int kk = i >> 6, cc = i & 63;
        o[cc * 128 + kk] = f2bf(Wf[i]);
    }
}

// ---------------- fp32 -> bf16 bulk convert ----------------
__global__ __launch_bounds__(256) void cvt_bf16_kernel(const float* __restrict__ in, ushort* __restrict__ o,
                                                       long n4) {
    for (long i = (long)blockIdx.x * 256 + threadIdx.x; i < n4; i += (long)gridDim.x * 256) {
        float4 x = ((const float4*)in)[i];
        ushort4 u;
        u.x = f2bf(x.x); u.y = f2bf(x.y); u.z = f2bf(x.z); u.w = f2bf(x.w);
        ((ushort4*)o)[i] = u;
    }
}

// ---------------- cluster histogram ----------------
__global__ __launch_bounds__(256) void hist_kernel(const int* __restrict__ clus, int* __restrict__ cnt, int n) {
    __shared__ int h[KCL];
    for (int i = threadIdx.x; i < KCL; i += 256) h[i] = 0;
    __syncthreads();
    for (long i = (long)blockIdx.x * 256 + threadIdx.x; i < n; i += (long)gridDim.x * 256)
        atomicAdd(&h[clus[i]], 1);
    __syncthreads();
    for (int i = threadIdx.x; i < KCL; i += 256) {
        int v = h[i];
        if (v) atomicAdd(&cnt[i], v);
    }
}

// ---------------- adaptive weights: softmax(feat @ aW[64,3], axis=1) ----------------
__global__ __launch_bounds__(256) void adp_kernel(const float* __restrict__ feat, const float* __restrict__ aW,
                                                  float* __restrict__ adp, int n) {
    __shared__ float w[192];
    for (int i = threadIdx.x; i < 192; i += 256) w[i] = aW[i];
    __syncthreads();
    for (long row = (long)blockIdx.x * 256 + threadIdx.x; row < n; row += (long)gridDim.x * 256) {
        const float4* fr = (const float4*)(feat + row * 64);
        float l0 = 0.f, l1 = 0.f, l2 = 0.f;
#pragma unroll
        for (int q = 0; q < 16; ++q) {
            float4 x = fr[q];
            int k = q * 4;
            l0 += x.x * w[k * 3 + 0] + x.y * w[k * 3 + 3] + x.z * w[k * 3 + 6] + x.w * w[k * 3 + 9];
            l1 += x.x * w[k * 3 + 1] + x.y * w[k * 3 + 4] + x.z * w[k * 3 + 7] + x.w * w[k * 3 + 10];
            l2 += x.x * w[k * 3 + 2] + x.y * w[k * 3 + 5] + x.z * w[k * 3 + 8] + x.w * w[k * 3 + 11];
        }
        float m = fmaxf(l0, fmaxf(l1, l2));
        float e0 = expf(l0 - m), e1 = expf(l1 - m), e2 = expf(l2 - m);
        float inv = 1.f / (e0 + e1 + e2);
        adp[row * 3 + 0] = e0 * inv;
        adp[row * 3 + 1] = e1 * inv;
        adp[row * 3 + 2] = e2 * inv;
    }
}

// ================= MFMA GEMM (n,64)@(64,64), 128-row tile =================
// SRC: 0 = bf16 input, 1 = fp32 plain, 2 = fp32 + bn(stats_in)+lrelu, 3 = fp32 / clamp(cnt,1)
// EPI: 0 = store fp32, 1 = store + column stats atomics, 2 = store(acc - MW[clus]) + global max
template <int SRC, int EPI>
__global__ __launch_bounds__(256) void gemm_mfma(const void* __restrict__ srcp, const ushort* __restrict__ Wt,
                                                 float* __restrict__ out, int n, int nstat,
                                                 const double* __restrict__ stats_in,
                                                 const float* __restrict__ gg, const float* __restrict__ bb,
                                                 const int* __restrict__ cnt, double* __restrict__ stats_out,
                                                 const float* __restrict__ MW, const int* __restrict__ clus,
                                                 unsigned* __restrict__ gmaxp) {
    __shared__ uint4 As[128 * 8];
    __shared__ uint4 Ws[64 * 8];
    __shared__ float sb[128];
    int t = threadIdx.x, lane = t & 63, w = t >> 6;
    int rb = blockIdx.x * 128;
    int arow = t >> 1, ah = t & 1;
    int wrow = t >> 2, wq = t & 3;
    const int l15 = lane & 15, lg = lane >> 4;

    if (SRC == 2) bn_sb(stats_in, gg, bb, nstat, sb);

    // stage W (transposed bf16: row = out col, contiguous K)
    {
        const uint4* srcw = (const uint4*)(Wt + (size_t)wrow * 64);
        int sw = wrow & 7;
        uint4* dst = Ws + wrow * 8;
        dst[wq ^ sw] = srcw[wq];
        dst[(wq + 4) ^ sw] = srcw[wq + 4];
    }
    // stage A
    int row = rb + arow;
    if (SRC == 0) {
        uint4 c0 = {0, 0, 0, 0}, c1 = c0, c2 = c0, c3 = c0;
        if (row < n) {
            const uint4* s = (const uint4*)((const ushort*)srcp + (size_t)row * 64) + ah * 4;
            c0 = s[0]; c1 = s[1]; c2 = s[2]; c3 = s[3];
        }
        int sw = arow & 7;
        uint4* dst = As + arow * 8;
        dst[(ah * 4 + 0) ^ sw] = c0;
        dst[(ah * 4 + 1) ^ sw] = c1;
        dst[(ah * 4 + 2) ^ sw] = c2;
        dst[(ah * 4 + 3) ^ sw] = c3;
    } else {
        float vals[32];
        if (row < n) {
            const float4* s = (const float4*)((const float*)srcp + (size_t)row * 64 + ah * 32);
            float inv = 1.f;
            if (SRC == 3) {
                float cf = (float)cnt[row];
                if (cf < 1.f) cf = 1.f;
                inv = 1.f / cf;
            }
#pragma unroll
            for (int q = 0; q < 8; ++q) {
                float4 x = s[q];
                vals[q * 4 + 0] = x.x; vals[q * 4 + 1] = x.y;
                vals[q * 4 + 2] = x.z; vals[q * 4 + 3] = x.w;
            }
            if (SRC == 2) {
#pragma unroll
                for (int i = 0; i < 32; ++i) {
                    int col = ah * 32 + i;
                    vals[i] = lrelu(vals[i] * sb[col] + sb[64 + col]);
                }
            } else if (SRC == 3) {
#pragma unroll
                for (int i = 0; i < 32; ++i) vals[i] *= inv;
            }
        } else {
#pragma unroll
            for (int i = 0; i < 32; ++i) vals[i] = 0.f;
        }
        int sw = arow & 7;
        uint4* dst = As + arow * 8;
#pragma unroll
        for (int c = 0; c < 4; ++c) {
            U8 u;
#pragma unroll
            for (int e = 0; e < 8; ++e) u.u[e] = f2bf(vals[c * 8 + e]);
            dst[(ah * 4 + c) ^ sw] = u.v;
        }
    }
    __syncthreads();

    f4v acc[2][4];
#pragma unroll
    for (int rf = 0; rf < 2; ++rf)
#pragma unroll
        for (int nf = 0; nf < 4; ++nf)
#pragma unroll
            for (int j = 0; j < 4; ++j) acc[rf][nf][j] = 0.f;

    int rowA0 = w * 32 + l15, rowA1 = rowA0 + 16;
    int swA0 = rowA0 & 7, swA1 = rowA1 & 7;
    const s8v* Av = (const s8v*)As;
    const s8v* Wv = (const s8v*)Ws;
#pragma unroll
    for (int kb = 0; kb < 2; ++kb) {
        int gch = kb * 4 + lg;
        s8v a0 = Av[rowA0 * 8 + (gch ^ swA0)];
        s8v a1 = Av[rowA1 * 8 + (gch ^ swA1)];
#pragma unroll
        for (int nf = 0; nf < 4; ++nf) {
            int col = nf * 16 + l15;
            s8v bf = Wv[col * 8 + (gch ^ (col & 7))];
            acc[0][nf] = __builtin_amdgcn_mfma_f32_16x16x32_bf16(a0, bf, acc[0][nf], 0, 0, 0);
            acc[1][nf] = __builtin_amdgcn_mfma_f32_16x16x32_bf16(a1, bf, acc[1][nf], 0, 0, 0);
        }
    }

    int base = rb + w * 32;
    if (EPI == 2) {
        float m = -INFINITY;
#pragma unroll
        for (int rf = 0; rf < 2; ++rf)
#pragma unroll
            for (int j = 0; j < 4; ++j) {
                int r = base + rf * 16 + lg * 4 + j;
                if (r < n) {
                    int c = clus[r];
                    const float* mwr = MW + (size_t)c * 64;
#pragma unroll
                    for (int nf = 0; nf < 4; ++nf) {
                        int col = nf * 16 + l15;
                        float v = acc[rf][nf][j] - mwr[col];
                        out[(size_t)r * 64 + col] = v;
                        m = fmaxf(m, v);
                    }
                }
            }
        __syncthreads();
        float* sp = (float*)As;
        sp[t] = m;
        __syncthreads();
        for (int s = 128; s > 0; s >>= 1) {
            if (t < s) sp[t] = fmaxf(sp[t], sp[t + s]);
            __syncthreads();
        }
        if (t == 0) atomicMax(gmaxp, encf(sp[0]));
    } else {
#pragma unroll
        for (int rf = 0; rf < 2; ++rf)
#pragma unroll
            for (int nf = 0; nf < 4; ++nf)
#pragma unroll
                for (int j = 0; j < 4; ++j) {
                    int r = base + rf * 16 + lg * 4 + j;
                    if (r < n) out[(size_t)r * 64 + nf * 16 + l15] = acc[rf][nf][j];
                }
        if (EPI == 1) {
            __syncthreads();
            float* sp = (float*)As;
            int gidx = w * 4 + lg;
#pragma unroll
            for (int nf = 0; nf < 4; ++nf) {
                int col = nf * 16 + l15;
                float s = 0.f, s2 = 0.f;
#pragma unroll
                for (int rf = 0; rf < 2; ++rf)
#pragma unroll
                    for (int j = 0; j < 4; ++j) {
                        int r = base + rf * 16 + lg * 4 + j;
                        if (r < n) {
                            float v = acc[rf][nf][j];
                            s += v;
                            s2 += v * v;
                        }
                    }
                sp[gidx * 64 + col] = s;
                sp[1024 + gidx * 64 + col] = s2;
            }
            __syncthreads();
            if (t < 64) {
                float s = 0.f, s2 = 0.f;
#pragma unroll
                for (int i = 0; i < 16; ++i) {
                    s += sp[i * 64 + t];
                    s2 += sp[1024 + i * 64 + t];
                }
                atomicAdd(&stats_out[t], (double)s);
                atomicAdd(&stats_out[64 + t], (double)s2);
            }
        }
    }
}

// ================= fuse GEMM: t3 = [bnlrelu(P3) | blend] @ Wf(128x64), stats epilogue =================
__global__ __launch_bounds__(256) void fuse_mfma(const float* __restrict__ P3, const double* __restrict__ statsP,
                                                 const float* __restrict__ gg, const float* __restrict__ bb, int n,
                                                 const float* __restrict__ adp, const int* __restrict__ clusters,
                                                 const float* __restrict__ s3_0, const float* __restrict__ s3_1,
                                                 const float* __restrict__ s3_2, const ushort* __restrict__ WfT,
                                                 float* __restrict__ out, double* __restrict__ stats_out) {
    __shared__ uint4 As[128 * 8];
    __shared__ uint4 Ws[64 * 8];
    __shared__ float sb[128];
    int t = threadIdx.x, lane = t & 63, w = t >> 6;
    int rb = blockIdx.x * 128;
    int arow = t >> 1, ah = t & 1;
    int wrow = t >> 2, wq = t & 3;
    const int l15 = lane & 15, lg = lane >> 4;

    bn_sb(statsP, gg, bb, n, sb);

    f4v acc[2][4];
#pragma unroll
    for (int rf = 0; rf < 2; ++rf)
#pragma unroll
        for (int nf = 0; nf < 4; ++nf)
#pragma unroll
            for (int j = 0; j < 4; ++j) acc[rf][nf][j] = 0.f;

    int rowA0 = w * 32 + l15, rowA1 = rowA0 + 16;
    int swA0 = rowA0 & 7, swA1 = rowA1 & 7;
    int row = rb + arow;

    for (int p = 0; p < 2; ++p) {
        if (p) __syncthreads();
        // stage A
        float vals[32];
        if (row < n) {
            if (p == 0) {
                const float4* s = (const float4*)(P3 + (size_t)row * 64 + ah * 32);
#pragma unroll
                for (int q = 0; q < 8; ++q) {
                    float4 x = s[q];
                    vals[q * 4 + 0] = x.x; vals[q * 4 + 1] = x.y;
                    vals[q * 4 + 2] = x.z; vals[q * 4 + 3] = x.w;
                }
#pragma unroll
                for (int i = 0; i < 32; ++i) {
                    int col = ah * 32 + i;
                    vals[i] = lrelu(vals[i] * sb[col] + sb[64 + col]);
                }
            } else {
                float a0 = adp[(size_t)row * 3 + 0], a1 = adp[(size_t)row * 3 + 1], a2 = adp[(size_t)row * 3 + 2];
                const float* r0 = s3_0 + (size_t)clusters[row] * 64 + ah * 32;
                const float* r1 = s3_1 + (size_t)clusters[(size_t)n + row] * 64 + ah * 32;
                const float* r2 = s3_2 + (size_t)clusters[2 * (size_t)n + row] * 64 + ah * 32;
#pragma unroll
                for (int i = 0; i < 32; ++i) vals[i] = a0 * r0[i] + a1 * r1[i] + a2 * r2[i];
            }
        } else {
#pragma unroll
            for (int i = 0; i < 32; ++i) vals[i] = 0.f;
        }
        {
            int sw = arow & 7;
            uint4* dst = As + arow * 8;
#pragma unroll
            for (int c = 0; c < 4; ++c) {
                U8 u;
#pragma unroll
                for (int e = 0; e < 8; ++e) u.u[e] = f2bf(vals[c * 8 + e]);
                dst[(ah * 4 + c) ^ sw] = u.v;
            }
        }
        // stage W slice (WfT: 64 rows x 128 k, phase p covers k in [64p, 64p+64))
        {
            const uint4* srcw = (const uint4*)(WfT + (size_t)wrow * 128);
            int sw = wrow & 7;
            uint4* dst = Ws + wrow * 8;
            dst[wq ^ sw] = srcw[p * 8 + wq];
            dst[(wq + 4) ^ sw] = srcw[p * 8 + wq + 4];
        }
        __syncthreads();
        const s8v* Av = (const s8v*)As;
        const s8v* Wv = (const s8v*)Ws;
#pragma unroll
        for (int kb = 0; kb < 2; ++kb) {
            int gch = kb * 4 + lg;
            s8v a0 = Av[rowA0 * 8 + (gch ^ swA0)];
            s8v a1 = Av[rowA1 * 8 + (gch ^ swA1)];
#pragma unroll
            for (int nf = 0; nf < 4; ++nf) {
                int col = nf * 16 + l15;
                s8v bf = Wv[col * 8 + (gch ^ (col & 7))];
                acc[0][nf] = __builtin_amdgcn_mfma_f32_16x16x32_bf16(a0, bf, acc[0][nf], 0, 0, 0);
                acc[1][nf] = __builtin_amdgcn_mfma_f32_16x16x32_bf16(a1, bf, acc[1][nf], 0, 0, 0);
            }
        }
    }
    int base = rb + w * 32;
#pragma unroll
    for (int rf = 0; rf < 2; ++rf)
#pragma unroll
        for (int nf = 0; nf < 4; ++nf)
#pragma unroll
            for (int j = 0; j < 4; ++j) {
                int r = base + rf * 16 + lg * 4 + j;
                if (r < n) out[(size_t)r * 64 + nf * 16 + l15] = acc[rf][nf][j];
            }
    __syncthreads();
    float* sp = (float*)As;
    int gidx = w * 4 + lg;
#pragma unroll
    for (int nf = 0; nf < 4; ++nf) {
        int col = nf * 16 + l15;
        float s = 0.f, s2 = 0.f;
#pragma unroll
        for (int rf = 0; rf < 2; ++rf)
#pragma unroll
            for (int j = 0; j < 4; ++j) {
                int r = base + rf * 16 + lg * 4 + j;
                if (r < n) {
                    float v = acc[rf][nf][j];
                    s += v;
                    s2 += v * v;
                }
            }
        sp[gidx * 64 + col] = s;
        sp[1024 + gidx * 64 + col] = s2;
    }
    __syncthreads();
    if (t < 64) {
        float s = 0.f, s2 = 0.f;
#pragma unroll
        for (int i = 0; i < 16; ++i) {
            s += sp[i * 64 + t];
            s2 += sp[1024 + i * 64 + t];
        }
        atomicAdd(&stats_out[t], (double)s);
        atomicAdd(&stats_out[64 + t], (double)s2);
    }
}

// ================= submanifold conv, bf16 MFMA, 128x64 tile, optional stats epilogue =================
template <int EPI>
__global__ __launch_bounds__(256) void subm_conv_mfma_kernel(const ushort* __restrict__ fin,
                                                             const int* __restrict__ nbr,
                                                             const ushort* __restrict__ Wt,
                                                             float* __restrict__ vout, int n,
                                                             double* __restrict__ stats_out) {
    __shared__ uint4 As[128 * 8];
    __shared__ uint4 Ws[64 * 8];
    int t = threadIdx.x;
    int lane = t & 63, w = t >> 6;
    int rb = blockIdx.x * 128;
    int arow = t >> 1, ah = t & 1;
    int wrow = t >> 2, wq = t & 3;
    const int l15 = lane & 15, lg = lane >> 4;
    int rowA0 = w * 32 + l15, rowA1 = rowA0 + 16;
    int swA0 = rowA0 & 7, swA1 = rowA1 & 7;

    f4v acc[2][4];
#pragma unroll
    for (int rf = 0; rf < 2; ++rf)
#pragma unroll
        for (int nf = 0; nf < 4; ++nf)
#pragma unroll
            for (int j = 0; j < 4; ++j) acc[rf][nf][j] = 0.f;

    for (int k = 0; k < 27; ++k) {
        __syncthreads();
        int gi = (rb + arow < n) ? nbr[(size_t)k * n + rb + arow] : -1;
        uint4 v0 = {0, 0, 0, 0}, v1 = {0, 0, 0, 0}, v2 = {0, 0, 0, 0}, v3 = {0, 0, 0, 0};
        if (gi >= 0) {
            const uint4* src = (const uint4*)(fin + (size_t)gi * 64) + ah * 4;
            v0 = src[0]; v1 = src[1]; v2 = src[2]; v3 = src[3];
        }
        {
            int sw = arow & 7;
            uint4* dst = As + arow * 8;
            dst[(ah * 4 + 0) ^ sw] = v0;
            dst[(ah * 4 + 1) ^ sw] = v1;
            dst[(ah * 4 + 2) ^ sw] = v2;
            dst[(ah * 4 + 3) ^ sw] = v3;
        }
        {
            const uint4* src = (const uint4*)(Wt + (size_t)k * 4096 + wrow * 64);
            int sw = wrow & 7;
            uint4* dst = Ws + wrow * 8;
            dst[wq ^ sw] = src[wq];
            dst[(wq + 4) ^ sw] = src[wq + 4];
        }
        __syncthreads();
        const s8v* Av = (const s8v*)As;
        const s8v* Wv = (const s8v*)Ws;
#pragma unroll
        for (int kb = 0; kb < 2; ++kb) {
            int g = kb * 4 + lg;
            s8v a0 = Av[rowA0 * 8 + (g ^ swA0)];
            s8v a1 = Av[rowA1 * 8 + (g ^ swA1)];
#pragma unroll
            for (int nf = 0; nf < 4; ++nf) {
                int col = nf * 16 + l15;
                s8v bf = Wv[col * 8 + (g ^ (col & 7))];
                acc[0][nf] = __builtin_amdgcn_mfma_f32_16x16x32_bf16(a0, bf, acc[0][nf], 0, 0, 0);
                acc[1][nf] = __builtin_amdgcn_mfma_f32_16x16x32_bf16(a1, bf, acc[1][nf], 0, 0, 0);
            }
        }
    }
    int base = rb + w * 32;
#pragma unroll
    for (int rf = 0; rf < 2; ++rf)
#pragma unroll
        for (int nf = 0; nf < 4; ++nf)
#pragma unroll
            for (int j = 0; j < 4; ++j) {
                int r = base + rf * 16 + lg * 4 + j;
                if (r < n) vout[(size_t)r * 64 + nf * 16 + l15] = acc[rf][nf][j];
            }
    if (EPI == 1) {
        __syncthreads();
        float* sp = (float*)As;
        int gidx = w * 4 + lg;
#pragma unroll
        for (int nf = 0; nf < 4; ++nf) {
            int col = nf * 16 + l15;
            float s = 0.f, s2 = 0.f;
#pragma unroll
            for (int rf = 0; rf < 2; ++rf)
#pragma unroll
                for (int j = 0; j < 4; ++j) {
                    int r = base + rf * 16 + lg * 4 + j;
                    if (r < n) {
                        float v = acc[rf][nf][j];
                        s += v;
                        s2 += v * v;
                    }
                }
            sp[gidx * 64 + col] = s;
            sp[1024 + gidx * 64 + col] = s2;
        }
        __syncthreads();
        if (t < 64) {
            float s = 0.f, s2 = 0.f;
#pragma unroll
            for (int i = 0; i < 16; ++i) {
                s += sp[i * 64 + t];
                s2 += sp[1024 + i * 64 + t];
            }
            atomicAdd(&stats_out[t], (double)s);
            atomicAdd(&stats_out[64 + t], (double)s2);
        }
    }
}

// ---------------- y = lrelu(bn(A)); seg[c] += y  (float4) ----------------
__global__ __launch_bounds__(256) void bnlrelu_segsum_kernel(const float* __restrict__ A,
                                                             const double* __restrict__ stats,
                                                             const float* __restrict__ g, const float* __restrict__ b,
                                                             float* __restrict__ seg, const int* __restrict__ clus,
                                                             int n) {
    __shared__ float sb[128];
    bn_sb(stats, g, b, n, sb);
    long total4 = (long)n * 16;
    for (long i = (long)blockIdx.x * 256 + threadIdx.x; i < total4; i += (long)gridDim.x * 256) {
        long row = i >> 4;
        int c0 = (int)(i & 15) * 4;
        float4 x = ((const float4*)A)[i];
        float* s = seg + (size_t)clus[row] * 64 + c0;
        atomicAdd(s + 0, lrelu(x.x * sb[c0 + 0] + sb[64 + c0 + 0]));
        atomicAdd(s + 1, lrelu(x.y * sb[c0 + 1] + sb[64 + c0 + 1]));
        atomicAdd(s + 2, lrelu(x.z * sb[c0 + 2] + sb[64 + c0 + 2]));
        atomicAdd(s + 3, lrelu(x.w * sb[c0 + 3] + sb[64 + c0 + 3]));
    }
}

// ---------------- D = exp(C - gmax) in place; seg2[c] += D ----------------
__global__ __launch_bounds__(256) void exp_segsum_kernel(float* __restrict__ C, const unsigned* __restrict__ gmaxp,
                                                         float* __restrict__ seg2, const int* __restrict__ clus,
                                                         int n) {
    float gm = decf(*gmaxp);
    long total4 = (long)n * 16;
    for (long i = (long)blockIdx.x * 256 + threadIdx.x; i < total4; i += (long)gridDim.x * 256) {
        long row = i >> 4;
        int c0 = (int)(i & 15) * 4;
        float4 x = ((float4*)C)[i];
        float4 y;
        y.x = expf(x.x - gm); y.y = expf(x.y - gm); y.z = expf(x.z - gm); y.w = expf(x.w - gm);
        ((float4*)C)[i] = y;
        float* s = seg2 + (size_t)clus[row] * 64 + c0;
        atomicAdd(s + 0, y.x);
        atomicAdd(s + 1, y.y);
        atomicAdd(s + 2, y.z);
        atomicAdd(s + 3, y.w);
    }
}

// ---------------- seg3[c] += lrelu(bn(E)) * D/(seg2[c]+1e-6) ----------------
__global__ __launch_bounds__(256) void pfpw_segsum_kernel(const float* __restrict__ E,
                                                          const double* __restrict__ stats,
                                                          const float* __restrict__ g, const float* __restrict__ b,
                                                          const float* __restrict__ D, const float* __restrict__ seg2,
                                                          float* __restrict__ seg3, const int* __restrict__ clus,
                                                          int n) {
    __shared__ float sb[128];
    bn_sb(stats, g, b, n, sb);
    long total4 = (long)n * 16;
    for (long i = (long)blockIdx.x * 256 + threadIdx.x; i < total4; i += (long)gridDim.x * 256) {
        long row = i >> 4;
        int c0 = (int)(i & 15) * 4;
        int c = clus[row];
        float4 e = ((const float4*)E)[i];
        float4 d = ((const float4*)D)[i];
        const float* s2 = seg2 + (size_t)c * 64 + c0;
        float* s3 = seg3 + (size_t)c * 64 + c0;
        atomicAdd(s3 + 0, lrelu(e.x * sb[c0 + 0] + sb[64 + c0 + 0]) * d.x / (s2[0] + 1e-6f));
        atomicAdd(s3 + 1, lrelu(e.y * sb[c0 + 1] + sb[64 + c0 + 1]) * d.y / (s2[1] + 1e-6f));
        atomicAdd(s3 + 2, lrelu(e.z * sb[c0 + 2] + sb[64 + c0 + 2]) * d.z / (s2[2] + 1e-6f));
        atomicAdd(s3 + 3, lrelu(e.w * sb[c0 + 3] + sb[64 + c0 + 3]) * d.w / (s2[3] + 1e-6f));
    }
}

// ---------------- f16 = bf16(lrelu(bn(t3)) + feat) ----------------
__global__ __launch_bounds__(256) void addfeat_kernel(const float* __restrict__ t3, const double* __restrict__ stats,
                                                      const float* __restrict__ g, const float* __restrict__ b,
                                                      const float* __restrict__ feat, ushort* __restrict__ f16,
                                                      int n) {
    __shared__ float sb[128];
    bn_sb(stats, g, b, n, sb);
    long total4 = (long)n * 16;
    for (long i = (long)blockIdx.x * 256 + threadIdx.x; i < total4; i += (long)gridDim.x * 256) {
        int c0 = (int)(i & 15) * 4;
        float4 x = ((const float4*)t3)[i];
        float4 fz = ((const float4*)feat)[i];
        ushort4 u;
        u.x = f2bf(lrelu(x.x * sb[c0 + 0] + sb[64 + c0 + 0]) + fz.x);
        u.y = f2bf(lrelu(x.y * sb[c0 + 1] + sb[64 + c0 + 1]) + fz.y);
        u.z = f2bf(lrelu(x.z * sb[c0 + 2] + sb[64 + c0 + 2]) + fz.z);
        u.w = f2bf(lrelu(x.w * sb[c0 + 3] + sb[64 + c0 + 3]) + fz.w);
        ((ushort4*)f16)[i] = u;
    }
}

// ---------------- o16 = bf16(lrelu(bn(v))) ----------------
__global__ __launch_bounds__(256) void bnlrelu_tobf16_kernel(const float* __restrict__ v,
                                                             const double* __restrict__ stats,
                                                             const float* __restrict__ g, const float* __restrict__ b,
                                                             ushort* __restrict__ o16, int n) {
    __shared__ float sb[128];
    bn_sb(stats, g, b, n, sb);
    long total4 = (long)n * 16;
    for (long i = (long)blockIdx.x * 256 + threadIdx.x; i < total4; i += (long)gridDim.x * 256) {
        int c0 = (int)(i & 15) * 4;
        float4 x = ((const float4*)v)[i];
        ushort4 u;
        u.x = f2bf(lrelu(x.x * sb[c0 + 0] + sb[64 + c0 + 0]));
        u.y = f2bf(lrelu(x.y * sb[c0 + 1] + sb[64 + c0 + 1]));
        u.z = f2bf(lrelu(x.z * sb[c0 + 2] + sb[64 + c0 + 2]));
        u.w = f2bf(lrelu(x.w * sb[c0 + 3] + sb[64 + c0 + 3]));
        ((ushort4*)o16)[i] = u;
    }
}

// ---------------- out = lrelu(bn(w) + f16) ----------------
__global__ __launch_bounds__(256) void final_kernel(const float* __restrict__ w, const double* __restrict__ stats,
                                                    const float* __restrict__ g, const float* __restrict__ b,
                                                    const ushort* __restrict__ f16, float* __restrict__ out, int n) {
    __shared__ float sb[128];
    bn_sb(stats, g, b, n, sb);
    long total4 = (long)n * 16;
    for (long i = (long)blockIdx.x * 256 + threadIdx.x; i < total4; i += (long)gridDim.x * 256) {
        int c0 = (int)(i & 15) * 4;
        float4 x = ((const float4*)w)[i];
        ushort4 u = ((const ushort4*)f16)[i];
        float4 y;
        y.x = lrelu(x.x * sb[c0 + 0] + sb[64 + c0 + 0] + bf2f(u.x));
        y.y = lrelu(x.y * sb[c0 + 1] + sb[64 + c0 + 1] + bf2f(u.y));
        y.z = lrelu(x.z * sb[c0 + 2] + sb[64 + c0 + 2] + bf2f(u.z));
        y.w = lrelu(x.w * sb[c0 + 3] + sb[64 + c0 + 3] + bf2f(u.w));
        ((float4*)out)[i] = y;
    }
}

extern "C" void kernel_launch(void* const* d_in, const int* in_sizes, int n_in,
                              void* d_out, int out_size, void* d_ws, size_t ws_size,
                              hipStream_t stream) {
    const float* feat = (const float*)d_in[0];
    const float* lw_W = (const float*)d_in[1];
    const float* lw_g = (const float*)d_in[2];
    const float* lw_b = (const float*)d_in[3];
    const float* w_W = (const float*)d_in[4];
    const float* proj_W = (const float*)d_in[5];
    const float* proj_g = (const float*)d_in[6];
    const float* proj_b = (const float*)d_in[7];
    const float* adaptive_W = (const float*)d_in[8];
    const float* fuse_W = (const float*)d_in[9];
    const float* fuse_g = (const float*)d_in[10];
    const float* fuse_b = (const float*)d_in[11];
    const float* conv1_W = (const float*)d_in[12];
    const float* bn1_g = (const float*)d_in[13];
    const float* bn1_b = (const float*)d_in[14];
    const float* conv2_W = (const float*)d_in[15];
    const float* bn2_g = (const float*)d_in[16];
    const float* bn2_b = (const float*)d_in[17];
    const int* clusters = (const int*)d_in[18];
    const int* nbr = (const int*)d_in[19];

    const int n = in_sizes[0] / 64;

    char* ws = (char*)d_ws;
    size_t off = 0;
    auto alloc = [&](size_t bytes) -> size_t {
        size_t o = off;
        off = (off + bytes + 255) & ~(size_t)255;
        return o;
    };
    // zeroed region
    size_t seg_off = alloc((size_t)9 * KCL * 64 * 4);
    size_t cnt_off = alloc((size_t)3 * KCL * 4);
    size_t stats_off = alloc((size_t)10 * 128 * 8);
    size_t gmax_off = alloc(16);
    size_t zbytes = off;
    // non-zeroed
    size_t adp_off = alloc((size_t)n * 3 * 4);
    size_t bufA_off = alloc((size_t)n * 64 * 4);
    size_t bufB_off = alloc((size_t)n * 64 * 4);
    size_t feat16_off = alloc((size_t)n * 64 * 2);
    size_t fbuf16_off = alloc((size_t)n * 64 * 2);
    size_t cbuf16_off = alloc((size_t)n * 64 * 2);
    size_t wt64_off = alloc((size_t)64 * 4096 * 2);
    size_t wfT_off = alloc((size_t)8192 * 2);
    size_t mw_off = alloc((size_t)KCL * 64 * 4);

    float* segs = (float*)(ws + seg_off);
    int* cnts = (int*)(ws + cnt_off);
    double* stats = (double*)(ws + stats_off);
    unsigned* gmax = (unsigned*)(ws + gmax_off);
    float* adp = (float*)(ws + adp_off);
    float* bufA = (float*)(ws + bufA_off);
    float* bufB = (float*)(ws + bufB_off);
    ushort* feat16 = (ushort*)(ws + feat16_off);
    ushort* fbuf16 = (ushort*)(ws + fbuf16_off);
    ushort* cbuf16 = (ushort*)(ws + cbuf16_off);
    ushort* wt64 = (ushort*)(ws + wt64_off);
    ushort* wfT = (ushort*)(ws + wfT_off);
    float* MW = (float*)(ws + mw_off);
    float* outp = (float*)d_out;

    const ushort* lwW16 = wt64;
    const ushort* wW16 = wt64 + (size_t)3 * 4096;
    const ushort* projW16 = wt64 + (size_t)6 * 4096;
    const ushort* conv1W16 = wt64 + (size_t)10 * 4096;
    const ushort* conv2W16 = wt64 + (size_t)37 * 4096;

    hipMemsetAsync(d_ws, 0, zbytes, stream);

    const int GEMM_BLK = (n + 127) / 128;
    const int EW_BLK = 2048;
    const long n4 = (long)n * 16;

    prep_wt64<<<64, 256, 0, stream>>>(lw_W, w_W, proj_W, conv1_W, conv2_W, wt64);
    prep_fuse<<<1, 256, 0, stream>>>(fuse_W, wfT);
    cvt_bf16_kernel<<<EW_BLK, 256, 0, stream>>>(feat, feat16, n4);
    adp_kernel<<<1024, 256, 0, stream>>>(feat, adaptive_W, adp, n);

    for (int i = 0; i < 3; ++i) {
        const int* clus = clusters + (size_t)i * n;
        int* cnt = cnts + (size_t)i * KCL;
        float* segB = segs + (size_t)(3 * i + 0) * KCL * 64;
        float* seg2 = segs + (size_t)(3 * i + 1) * KCL * 64;
        float* seg3 = segs + (size_t)(3 * i + 2) * KCL * 64;
        double* stA = stats + (size_t)(2 * i + 0) * 128;
        double* stE = stats + (size_t)(2 * i + 1) * 128;

        hist_kernel<<<256, 256, 0, stream>>>(clus, cnt, n);
        // A = feat16 @ lw_W[i], + colstats
        gemm_mfma<0, 1><<<GEMM_BLK, 256, 0, stream>>>(feat16, lwW16 + (size_t)i * 4096, bufA, n, n,
                                                      nullptr, nullptr, nullptr, nullptr, stA,
                                                      nullptr, nullptr, nullptr);
        // segB[c] += lrelu(bn(A))
        bnlrelu_segsum_kernel<<<EW_BLK, 256, 0, stream>>>(bufA, stA, lw_g + i * 64, lw_b + i * 64,
                                                          segB, clus, n);
        // MW = (segB/clamp(cnt,1)) @ w_W[i]   (2048 rows)
        gemm_mfma<3, 0><<<16, 256, 0, stream>>>(segB, wW16 + (size_t)i * 4096, MW, KCL, KCL,
                                                nullptr, nullptr, nullptr, cnt, nullptr,
                                                nullptr, nullptr, nullptr);
        // C = bnlrelu(A) @ w_W[i] - MW[c], + global max
        gemm_mfma<2, 2><<<GEMM_BLK, 256, 0, stream>>>(bufA, wW16 + (size_t)i * 4096, bufB, n, n,
                                                      stA, lw_g + i * 64, lw_b + i * 64, nullptr, nullptr,
                                                      MW, clus, gmax + i);
        // D = exp(C - gmax); seg2[c] += D
        exp_segsum_kernel<<<EW_BLK, 256, 0, stream>>>(bufB, gmax + i, seg2, clus, n);
        // E = feat16 @ proj_W[i], + colstats
        gemm_mfma<0, 1><<<GEMM_BLK, 256, 0, stream>>>(feat16, projW16 + (size_t)i * 4096, bufA, n, n,
                                                      nullptr, nullptr, nullptr, nullptr, stE,
                                                      nullptr, nullptr, nullptr);
        // seg3[c] += lrelu(bn(E)) * D/(seg2[c]+1e-6)
        pfpw_segsum_kernel<<<EW_BLK, 256, 0, stream>>>(bufA, stE, proj_g + i * 64, proj_b + i * 64,
                                                       bufB, seg2, seg3, clus, n);
    }

    // P3 = feat16 @ proj_W[3], + colstats
    gemm_mfma<0, 1><<<GEMM_BLK, 256, 0, stream>>>(feat16, projW16 + (size_t)3 * 4096, bufA, n, n,
                                                  nullptr, nullptr, nullptr, nullptr, stats + 6 * 128,
                                                  nullptr, nullptr, nullptr);
    // t3 = [bnlrelu(P3) | blend(adp,seg3)] @ fuse_W, + colstats
    fuse_mfma<<<GEMM_BLK, 256, 0, stream>>>(bufA, stats + 6 * 128, proj_g + 192, proj_b + 192, n,
                                            adp, clusters,
                                            segs + (size_t)2 * KCL * 64,
                                            segs + (size_t)5 * KCL * 64,
                                            segs + (size_t)8 * KCL * 64,
                                            wfT, bufB, stats + 7 * 128);
    // f = lrelu(bn(t3)) + feat  (bf16)
    addfeat_kernel<<<EW_BLK, 256, 0, stream>>>(bufB, stats + 7 * 128, fuse_g, fuse_b, feat, fbuf16, n);

    // conv1 (+stats) -> d_out scratch, then bn1+lrelu -> bf16
    subm_conv_mfma_kernel<1><<<GEMM_BLK, 256, 0, stream>>>(fbuf16, nbr, conv1W16, outp, n, stats + 8 * 128);
    bnlrelu_tobf16_kernel<<<EW_BLK, 256, 0, stream>>>(outp, stats + 8 * 128, bn1_g, bn1_b, cbuf16, n);

    // conv2 (+stats) -> bufA, then out = lrelu(bn2 + f)
    subm_conv_mfma_kernel<1><<<GEMM_BLK, 256, 0, stream>>>(cbuf16, nbr, conv2W16, bufA, n, stats + 9 * 128);
    final_kernel<<<EW_BLK, 256, 0, stream>>>(bufA, stats + 9 * 128, bn2_g, bn2_b, fbuf16, outp, n);
}

// Round 4
// 839.850 us; speedup vs baseline: 2.2673x; 2.2673x over previous
//
#include <hip/hip_runtime.h>
#include <hip/hip_bf16.h>
#include <math.h>

#define KCL 2048
#define LRELU_NEG 0.01f
#define EPSBN 1e-5f

using s8v = __attribute__((ext_vector_type(8))) short;   // 8 bf16 (4 VGPRs)
using f4v = __attribute__((ext_vector_type(4))) float;   // MFMA accumulator

union U8 { ushort u[8]; uint4 v; };

__device__ __forceinline__ float lrelu(float x) { return x > 0.f ? x : LRELU_NEG * x; }
__device__ __forceinline__ ushort f2bf(float f) {
    __hip_bfloat16 h = __float2bfloat16(f);
    return *reinterpret_cast<ushort*>(&h);
}
__device__ __forceinline__ float bf2f(ushort u) { return __uint_as_float(((unsigned)u) << 16); }

// monotonic float->uint encoding for atomicMax over mixed-sign floats
__device__ __forceinline__ unsigned encf(float f) {
    unsigned u = __float_as_uint(f);
    return (u & 0x80000000u) ? ~u : (u | 0x80000000u);
}
__device__ __forceinline__ float decf(unsigned u) {
    return __uint_as_float((u & 0x80000000u) ? (u & 0x7fffffffu) : ~u);
}

// finalize BN stats into LDS scale/bias: y = x*sb[col] + sb[64+col]
__device__ __forceinline__ void bn_sb(const double* __restrict__ stats, const float* __restrict__ g,
                                      const float* __restrict__ b, int n, float* sb) {
    int t = threadIdx.x;
    if (t < 64) {
        float mean = (float)(stats[t] / n);
        float ex2 = (float)(stats[64 + t] / n);
        float var = fmaxf(ex2 - mean * mean, 0.f);
        float rstd = rsqrtf(var + EPSBN);
        float sc = rstd * g[t];
        sb[t] = sc;
        sb[64 + t] = b[t] - mean * sc;
    }
    __syncthreads();
}

// ---------------- weight prep: 64 matrices of 64x64, transposed -> bf16 ----------------
__global__ __launch_bounds__(256) void prep_wt64(const float* __restrict__ lw, const float* __restrict__ wW,
                                                 const float* __restrict__ proj, const float* __restrict__ c1,
                                                 const float* __restrict__ c2, ushort* __restrict__ wt) {
    int bk = blockIdx.x;
    const float* W;
    if (bk < 3) W = lw + (size_t)bk * 4096;
    else if (bk < 6) W = wW + (size_t)(bk - 3) * 4096;
    else if (bk < 10) W = proj + (size_t)(bk - 6) * 4096;
    else if (bk < 37) W = c1 + (size_t)(bk - 10) * 4096;
    else W = c2 + (size_t)(bk - 37) * 4096;
    ushort* o = wt + (size_t)bk * 4096;
    for (int i = threadIdx.x; i < 4096; i += 256) {
        int kk = i >> 6, cc = i & 63;
        o[cc * 64 + kk] = f2bf(W[i]);
    }
}

__global__ __launch_bounds__(256) void prep_fuse(const float* __restrict__ Wf, ushort* __restrict__ o) {
    for (int i = threadIdx.x; i < 8192; i += 256) {
        int kk = i >> 6, cc = i & 63;
        o[cc * 128 + kk] = f2bf(Wf[i]);
    }
}

// ---------------- fp32 -> bf16 bulk convert ----------------
__global__ __launch_bounds__(256) void cvt_bf16_kernel(const float* __restrict__ in, ushort* __restrict__ o,
                                                       long n4) {
    for (long i = (long)blockIdx.x * 256 + threadIdx.x; i < n4; i += (long)gridDim.x * 256) {
        float4 x = ((const float4*)in)[i];
        ushort4 u;
        u.x = f2bf(x.x); u.y = f2bf(x.y); u.z = f2bf(x.z); u.w = f2bf(x.w);
        ((ushort4*)o)[i] = u;
    }
}

// ---------------- cluster histogram, all 3 levels (block handles level = blockIdx%3) ----------------
__global__ __launch_bounds__(256) void hist3_kernel(const int* __restrict__ clusters, int* __restrict__ cnt,
                                                    int n) {
    __shared__ int h[KCL];
    int l = blockIdx.x % 3;
    int nb = gridDim.x / 3, bi = blockIdx.x / 3;
    for (int i = threadIdx.x; i < KCL; i += 256) h[i] = 0;
    __syncthreads();
    const int* cl = clusters + (size_t)l * n;
    for (long i = (long)bi * 256 + threadIdx.x; i < n; i += (long)nb * 256)
        atomicAdd(&h[cl[i]], 1);
    __syncthreads();
    for (int i = threadIdx.x; i < KCL; i += 256) {
        int v = h[i];
        if (v) atomicAdd(&cnt[l * KCL + i], v);
    }
}

// ---------------- exclusive scan of 2048 counts per level -> absolute offsets + cursor ----------------
__global__ __launch_bounds__(256) void scan_kernel(const int* __restrict__ cnt, int* __restrict__ off,
                                                   int* __restrict__ cursor, int n) {
    int l = blockIdx.x;
    const int* c = cnt + l * KCL;
    __shared__ int part[256];
    __shared__ int pref[256];
    int t = threadIdx.x;
    int base = t * 8;
    int v[8];
    int s = 0;
#pragma unroll
    for (int j = 0; j < 8; ++j) { v[j] = c[base + j]; s += v[j]; }
    part[t] = s;
    __syncthreads();
    if (t == 0) {
        int acc = 0;
        for (int i = 0; i < 256; ++i) { pref[i] = acc; acc += part[i]; }
    }
    __syncthreads();
    int acc = pref[t] + l * n;   // absolute position into perm[3n]
#pragma unroll
    for (int j = 0; j < 8; ++j) {
        off[l * KCL + base + j] = acc;
        cursor[l * KCL + base + j] = acc;
        acc += v[j];
    }
}

// ---------------- scatter rows into cluster-sorted perm (all 3 levels) ----------------
__global__ __launch_bounds__(256) void scatter_kernel(const int* __restrict__ clusters, int* __restrict__ cursor,
                                                      int* __restrict__ perm, int n) {
    long n3 = (long)n * 3;
    for (long i = (long)blockIdx.x * 256 + threadIdx.x; i < n3; i += (long)gridDim.x * 256) {
        int l = (i >= n) + (i >= 2 * (long)n);
        int c = clusters[i];
        int pos = atomicAdd(&cursor[l * KCL + c], 1);
        perm[pos] = (int)(i - (long)l * n);
    }
}

// ---------------- adaptive weights: softmax(feat @ aW[64,3], axis=1) ----------------
__global__ __launch_bounds__(256) void adp_kernel(const float* __restrict__ feat, const float* __restrict__ aW,
                                                  float* __restrict__ adp, int n) {
    __shared__ float w[192];
    for (int i = threadIdx.x; i < 192; i += 256) w[i] = aW[i];
    __syncthreads();
    for (long row = (long)blockIdx.x * 256 + threadIdx.x; row < n; row += (long)gridDim.x * 256) {
        const float4* fr = (const float4*)(feat + row * 64);
        float l0 = 0.f, l1 = 0.f, l2 = 0.f;
#pragma unroll
        for (int q = 0; q < 16; ++q) {
            float4 x = fr[q];
            int k = q * 4;
            l0 += x.x * w[k * 3 + 0] + x.y * w[k * 3 + 3] + x.z * w[k * 3 + 6] + x.w * w[k * 3 + 9];
            l1 += x.x * w[k * 3 + 1] + x.y * w[k * 3 + 4] + x.z * w[k * 3 + 7] + x.w * w[k * 3 + 10];
            l2 += x.x * w[k * 3 + 2] + x.y * w[k * 3 + 5] + x.z * w[k * 3 + 8] + x.w * w[k * 3 + 11];
        }
        float m = fmaxf(l0, fmaxf(l1, l2));
        float e0 = expf(l0 - m), e1 = expf(l1 - m), e2 = expf(l2 - m);
        float inv = 1.f / (e0 + e1 + e2);
        adp[row * 3 + 0] = e0 * inv;
        adp[row * 3 + 1] = e1 * inv;
        adp[row * 3 + 2] = e2 * inv;
    }
}

// ================= MFMA GEMM (n,64)@(64,64), 128-row tile =================
// SRC: 0 = bf16 input, 1 = fp32 plain, 2 = fp32 + bn(stats_in)+lrelu
// EPI: 0 = store fp32, 1 = store + column stats atomics, 2 = store(acc - MW[clus]) + global max
template <int SRC, int EPI>
__global__ __launch_bounds__(256) void gemm_mfma(const void* __restrict__ srcp, const ushort* __restrict__ Wt,
                                                 float* __restrict__ out, int n, int nstat,
                                                 const double* __restrict__ stats_in,
                                                 const float* __restrict__ gg, const float* __restrict__ bb,
                                                 double* __restrict__ stats_out,
                                                 const float* __restrict__ MW, const int* __restrict__ clus,
                                                 unsigned* __restrict__ gmaxp) {
    __shared__ uint4 As[128 * 8];
    __shared__ uint4 Ws[64 * 8];
    __shared__ float sb[128];
    int t = threadIdx.x, lane = t & 63, w = t >> 6;
    int rb = blockIdx.x * 128;
    int arow = t >> 1, ah = t & 1;
    int wrow = t >> 2, wq = t & 3;
    const int l15 = lane & 15, lg = lane >> 4;

    if (SRC == 2) bn_sb(stats_in, gg, bb, nstat, sb);

    // stage W (transposed bf16: row = out col, contiguous K)
    {
        const uint4* srcw = (const uint4*)(Wt + (size_t)wrow * 64);
        int sw = wrow & 7;
        uint4* dst = Ws + wrow * 8;
        dst[wq ^ sw] = srcw[wq];
        dst[(wq + 4) ^ sw] = srcw[wq + 4];
    }
    // stage A
    int row = rb + arow;
    if (SRC == 0) {
        uint4 c0 = {0, 0, 0, 0}, c1 = c0, c2 = c0, c3 = c0;
        if (row < n) {
            const uint4* s = (const uint4*)((const ushort*)srcp + (size_t)row * 64) + ah * 4;
            c0 = s[0]; c1 = s[1]; c2 = s[2]; c3 = s[3];
        }
        int sw = arow & 7;
        uint4* dst = As + arow * 8;
        dst[(ah * 4 + 0) ^ sw] = c0;
        dst[(ah * 4 + 1) ^ sw] = c1;
        dst[(ah * 4 + 2) ^ sw] = c2;
        dst[(ah * 4 + 3) ^ sw] = c3;
    } else {
        float vals[32];
        if (row < n) {
            const float4* s = (const float4*)((const float*)srcp + (size_t)row * 64 + ah * 32);
#pragma unroll
            for (int q = 0; q < 8; ++q) {
                float4 x = s[q];
                vals[q * 4 + 0] = x.x; vals[q * 4 + 1] = x.y;
                vals[q * 4 + 2] = x.z; vals[q * 4 + 3] = x.w;
            }
            if (SRC == 2) {
#pragma unroll
                for (int i = 0; i < 32; ++i) {
                    int col = ah * 32 + i;
                    vals[i] = lrelu(vals[i] * sb[col] + sb[64 + col]);
                }
            }
        } else {
#pragma unroll
            for (int i = 0; i < 32; ++i) vals[i] = 0.f;
        }
        int sw = arow & 7;
        uint4* dst = As + arow * 8;
#pragma unroll
        for (int c = 0; c < 4; ++c) {
            U8 u;
#pragma unroll
            for (int e = 0; e < 8; ++e) u.u[e] = f2bf(vals[c * 8 + e]);
            dst[(ah * 4 + c) ^ sw] = u.v;
        }
    }
    __syncthreads();

    f4v acc[2][4];
#pragma unroll
    for (int rf = 0; rf < 2; ++rf)
#pragma unroll
        for (int nf = 0; nf < 4; ++nf)
#pragma unroll
            for (int j = 0; j < 4; ++j) acc[rf][nf][j] = 0.f;

    int rowA0 = w * 32 + l15, rowA1 = rowA0 + 16;
    int swA0 = rowA0 & 7, swA1 = rowA1 & 7;
    const s8v* Av = (const s8v*)As;
    const s8v* Wv = (const s8v*)Ws;
#pragma unroll
    for (int kb = 0; kb < 2; ++kb) {
        int gch = kb * 4 + lg;
        s8v a0 = Av[rowA0 * 8 + (gch ^ swA0)];
        s8v a1 = Av[rowA1 * 8 + (gch ^ swA1)];
#pragma unroll
        for (int nf = 0; nf < 4; ++nf) {
            int col = nf * 16 + l15;
            s8v bf = Wv[col * 8 + (gch ^ (col & 7))];
            acc[0][nf] = __builtin_amdgcn_mfma_f32_16x16x32_bf16(a0, bf, acc[0][nf], 0, 0, 0);
            acc[1][nf] = __builtin_amdgcn_mfma_f32_16x16x32_bf16(a1, bf, acc[1][nf], 0, 0, 0);
        }
    }

    int base = rb + w * 32;
    if (EPI == 2) {
        float m = -INFINITY;
#pragma unroll
        for (int rf = 0; rf < 2; ++rf)
#pragma unroll
            for (int j = 0; j < 4; ++j) {
                int r = base + rf * 16 + lg * 4 + j;
                if (r < n) {
                    int c = clus[r];
                    const float* mwr = MW + (size_t)c * 64;
#pragma unroll
                    for (int nf = 0; nf < 4; ++nf) {
                        int col = nf * 16 + l15;
                        float v = acc[rf][nf][j] - mwr[col];
                        out[(size_t)r * 64 + col] = v;
                        m = fmaxf(m, v);
                    }
                }
            }
        __syncthreads();
        float* sp = (float*)As;
        sp[t] = m;
        __syncthreads();
        for (int s = 128; s > 0; s >>= 1) {
            if (t < s) sp[t] = fmaxf(sp[t], sp[t + s]);
            __syncthreads();
        }
        if (t == 0) atomicMax(gmaxp, encf(sp[0]));
    } else {
#pragma unroll
        for (int rf = 0; rf < 2; ++rf)
#pragma unroll
            for (int nf = 0; nf < 4; ++nf)
#pragma unroll
                for (int j = 0; j < 4; ++j) {
                    int r = base + rf * 16 + lg * 4 + j;
                    if (r < n) out[(size_t)r * 64 + nf * 16 + l15] = acc[rf][nf][j];
                }
        if (EPI == 1) {
            __syncthreads();
            float* sp = (float*)As;
            int gidx = w * 4 + lg;
#pragma unroll
            for (int nf = 0; nf < 4; ++nf) {
                int col = nf * 16 + l15;
                float s = 0.f, s2 = 0.f;
#pragma unroll
                for (int rf = 0; rf < 2; ++rf)
#pragma unroll
                    for (int j = 0; j < 4; ++j) {
                        int r = base + rf * 16 + lg * 4 + j;
                        if (r < n) {
                            float v = acc[rf][nf][j];
                            s += v;
                            s2 += v * v;
                        }
                    }
                sp[gidx * 64 + col] = s;
                sp[1024 + gidx * 64 + col] = s2;
            }
            __syncthreads();
            if (t < 64) {
                float s = 0.f, s2 = 0.f;
#pragma unroll
                for (int i = 0; i < 16; ++i) {
                    s += sp[i * 64 + t];
                    s2 += sp[1024 + i * 64 + t];
                }
                atomicAdd(&stats_out[t], (double)s);
                atomicAdd(&stats_out[64 + t], (double)s2);
            }
        }
    }
}

// ================= per-cluster reduction kernels (block = cluster, zero atomics) =================

// meanB[c] = (1/clamp(cnt,1)) * sum_{rows in c} lrelu(bn(A))
__global__ __launch_bounds__(256) void reduce_mean_kernel(const float* __restrict__ A,
                                                          const double* __restrict__ stats,
                                                          const float* __restrict__ g, const float* __restrict__ b,
                                                          int n, const int* __restrict__ cnt,
                                                          const int* __restrict__ off, const int* __restrict__ perm,
                                                          float* __restrict__ meanB) {
    __shared__ float sb[128];
    bn_sb(stats, g, b, n, sb);
    int c = blockIdx.x;
    int t = threadIdx.x, col = t & 63, rg = t >> 6;
    int o = off[c], m = cnt[c];
    float acc = 0.f;
    float sc = sb[col], bi = sb[64 + col];
    for (int j = rg; j < m; j += 4) {
        int row = perm[o + j];
        acc += lrelu(A[(size_t)row * 64 + col] * sc + bi);
    }
    __shared__ float red[256];
    red[t] = acc;
    __syncthreads();
    if (t < 64) {
        float s = red[t] + red[t + 64] + red[t + 128] + red[t + 192];
        float cf = (float)m;
        if (cf < 1.f) cf = 1.f;
        meanB[(size_t)c * 64 + col] = s / cf;
    }
}

// seg2[c] = sum_{rows in c} exp(C - gmax)
__global__ __launch_bounds__(256) void reduce_exp_kernel(const float* __restrict__ C,
                                                         const unsigned* __restrict__ gmaxp,
                                                         const int* __restrict__ cnt, const int* __restrict__ off,
                                                         const int* __restrict__ perm, float* __restrict__ seg2) {
    int c = blockIdx.x;
    int t = threadIdx.x, col = t & 63, rg = t >> 6;
    float gm = decf(*gmaxp);
    int o = off[c], m = cnt[c];
    float acc = 0.f;
    for (int j = rg; j < m; j += 4) {
        int row = perm[o + j];
        acc += expf(C[(size_t)row * 64 + col] - gm);
    }
    __shared__ float red[256];
    red[t] = acc;
    __syncthreads();
    if (t < 64) seg2[(size_t)c * 64 + col] = red[t] + red[t + 64] + red[t + 128] + red[t + 192];
}

// seg3[c] = (1/(seg2[c]+1e-6)) * sum_{rows in c} lrelu(bn(E)) * exp(C - gmax)
__global__ __launch_bounds__(256) void reduce_pf_kernel(const float* __restrict__ E,
                                                        const double* __restrict__ stats,
                                                        const float* __restrict__ g, const float* __restrict__ b,
                                                        int n, const float* __restrict__ C,
                                                        const unsigned* __restrict__ gmaxp,
                                                        const float* __restrict__ seg2,
                                                        const int* __restrict__ cnt, const int* __restrict__ off,
                                                        const int* __restrict__ perm, float* __restrict__ seg3) {
    __shared__ float sb[128];
    bn_sb(stats, g, b, n, sb);
    int c = blockIdx.x;
    int t = threadIdx.x, col = t & 63, rg = t >> 6;
    float gm = decf(*gmaxp);
    float inv = 1.f / (seg2[(size_t)c * 64 + col] + 1e-6f);
    int o = off[c], m = cnt[c];
    float acc = 0.f;
    float sc = sb[col], bi = sb[64 + col];
    for (int j = rg; j < m; j += 4) {
        int row = perm[o + j];
        float pf = lrelu(E[(size_t)row * 64 + col] * sc + bi);
        float d = expf(C[(size_t)row * 64 + col] - gm);
        acc += pf * d;
    }
    __shared__ float red[256];
    red[t] = acc;
    __syncthreads();
    if (t < 64)
        seg3[(size_t)c * 64 + col] = (red[t] + red[t + 64] + red[t + 128] + red[t + 192]) * inv;
}

// ================= fuse GEMM: t3 = [bnlrelu(P3) | blend] @ Wf(128x64), stats epilogue =================
__global__ __launch_bounds__(256) void fuse_mfma(const float* __restrict__ P3, const double* __restrict__ statsP,
                                                 const float* __restrict__ gg, const float* __restrict__ bb, int n,
                                                 const float* __restrict__ adp, const int* __restrict__ clusters,
                                                 const float* __restrict__ s3_0, const float* __restrict__ s3_1,
                                                 const float* __restrict__ s3_2, const ushort* __restrict__ WfT,
                                                 float* __restrict__ out, double* __restrict__ stats_out) {
    __shared__ uint4 As[128 * 8];
    __shared__ uint4 Ws[64 * 8];
    __shared__ float sb[128];
    int t = threadIdx.x, lane = t & 63, w = t >> 6;
    int rb = blockIdx.x * 128;
    int arow = t >> 1, ah = t & 1;
    int wrow = t >> 2, wq = t & 3;
    const int l15 = lane & 15, lg = lane >> 4;

    bn_sb(statsP, gg, bb, n, sb);

    f4v acc[2][4];
#pragma unroll
    for (int rf = 0; rf < 2; ++rf)
#pragma unroll
        for (int nf = 0; nf < 4; ++nf)
#pragma unroll
            for (int j = 0; j < 4; ++j) acc[rf][nf][j] = 0.f;

    int rowA0 = w * 32 + l15, rowA1 = rowA0 + 16;
    int swA0 = rowA0 & 7, swA1 = rowA1 & 7;
    int row = rb + arow;

    for (int p = 0; p < 2; ++p) {
        if (p) __syncthreads();
        float vals[32];
        if (row < n) {
            if (p == 0) {
                const float4* s = (const float4*)(P3 + (size_t)row * 64 + ah * 32);
#pragma unroll
                for (int q = 0; q < 8; ++q) {
                    float4 x = s[q];
                    vals[q * 4 + 0] = x.x; vals[q * 4 + 1] = x.y;
                    vals[q * 4 + 2] = x.z; vals[q * 4 + 3] = x.w;
                }
#pragma unroll
                for (int i = 0; i < 32; ++i) {
                    int col = ah * 32 + i;
                    vals[i] = lrelu(vals[i] * sb[col] + sb[64 + col]);
                }
            } else {
                float a0 = adp[(size_t)row * 3 + 0], a1 = adp[(size_t)row * 3 + 1], a2 = adp[(size_t)row * 3 + 2];
                const float* r0 = s3_0 + (size_t)clusters[row] * 64 + ah * 32;
                const float* r1 = s3_1 + (size_t)clusters[(size_t)n + row] * 64 + ah * 32;
                const float* r2 = s3_2 + (size_t)clusters[2 * (size_t)n + row] * 64 + ah * 32;
#pragma unroll
                for (int i = 0; i < 32; ++i) vals[i] = a0 * r0[i] + a1 * r1[i] + a2 * r2[i];
            }
        } else {
#pragma unroll
            for (int i = 0; i < 32; ++i) vals[i] = 0.f;
        }
        {
            int sw = arow & 7;
            uint4* dst = As + arow * 8;
#pragma unroll
            for (int c = 0; c < 4; ++c) {
                U8 u;
#pragma unroll
                for (int e = 0; e < 8; ++e) u.u[e] = f2bf(vals[c * 8 + e]);
                dst[(ah * 4 + c) ^ sw] = u.v;
            }
        }
        {
            const uint4* srcw = (const uint4*)(WfT + (size_t)wrow * 128);
            int sw = wrow & 7;
            uint4* dst = Ws + wrow * 8;
            dst[wq ^ sw] = srcw[p * 8 + wq];
            dst[(wq + 4) ^ sw] = srcw[p * 8 + wq + 4];
        }
        __syncthreads();
        const s8v* Av = (const s8v*)As;
        const s8v* Wv = (const s8v*)Ws;
#pragma unroll
        for (int kb = 0; kb < 2; ++kb) {
            int gch = kb * 4 + lg;
            s8v a0 = Av[rowA0 * 8 + (gch ^ swA0)];
            s8v a1 = Av[rowA1 * 8 + (gch ^ swA1)];
#pragma unroll
            for (int nf = 0; nf < 4; ++nf) {
                int col = nf * 16 + l15;
                s8v bf = Wv[col * 8 + (gch ^ (col & 7))];
                acc[0][nf] = __builtin_amdgcn_mfma_f32_16x16x32_bf16(a0, bf, acc[0][nf], 0, 0, 0);
                acc[1][nf] = __builtin_amdgcn_mfma_f32_16x16x32_bf16(a1, bf, acc[1][nf], 0, 0, 0);
            }
        }
    }
    int base = rb + w * 32;
#pragma unroll
    for (int rf = 0; rf < 2; ++rf)
#pragma unroll
        for (int nf = 0; nf < 4; ++nf)
#pragma unroll
            for (int j = 0; j < 4; ++j) {
                int r = base + rf * 16 + lg * 4 + j;
                if (r < n) out[(size_t)r * 64 + nf * 16 + l15] = acc[rf][nf][j];
            }
    __syncthreads();
    float* sp = (float*)As;
    int gidx = w * 4 + lg;
#pragma unroll
    for (int nf = 0; nf < 4; ++nf) {
        int col = nf * 16 + l15;
        float s = 0.f, s2 = 0.f;
#pragma unroll
        for (int rf = 0; rf < 2; ++rf)
#pragma unroll
            for (int j = 0; j < 4; ++j) {
                int r = base + rf * 16 + lg * 4 + j;
                if (r < n) {
                    float v = acc[rf][nf][j];
                    s += v;
                    s2 += v * v;
                }
            }
        sp[gidx * 64 + col] = s;
        sp[1024 + gidx * 64 + col] = s2;
    }
    __syncthreads();
    if (t < 64) {
        float s = 0.f, s2 = 0.f;
#pragma unroll
        for (int i = 0; i < 16; ++i) {
            s += sp[i * 64 + t];
            s2 += sp[1024 + i * 64 + t];
        }
        atomicAdd(&stats_out[t], (double)s);
        atomicAdd(&stats_out[64 + t], (double)s2);
    }
}

// ================= submanifold conv, bf16 MFMA, 128x64 tile, optional stats epilogue =================
template <int EPI>
__global__ __launch_bounds__(256) void subm_conv_mfma_kernel(const ushort* __restrict__ fin,
                                                             const int* __restrict__ nbr,
                                                             const ushort* __restrict__ Wt,
                                                             float* __restrict__ vout, int n,
                                                             double* __restrict__ stats_out) {
    __shared__ uint4 As[128 * 8];
    __shared__ uint4 Ws[64 * 8];
    int t = threadIdx.x;
    int lane = t & 63, w = t >> 6;
    int rb = blockIdx.x * 128;
    int arow = t >> 1, ah = t & 1;
    int wrow = t >> 2, wq = t & 3;
    const int l15 = lane & 15, lg = lane >> 4;
    int rowA0 = w * 32 + l15, rowA1 = rowA0 + 16;
    int swA0 = rowA0 & 7, swA1 = rowA1 & 7;

    f4v acc[2][4];
#pragma unroll
    for (int rf = 0; rf < 2; ++rf)
#pragma unroll
        for (int nf = 0; nf < 4; ++nf)
#pragma unroll
            for (int j = 0; j < 4; ++j) acc[rf][nf][j] = 0.f;

    for (int k = 0; k < 27; ++k) {
        __syncthreads();
        int gi = (rb + arow < n) ? nbr[(size_t)k * n + rb + arow] : -1;
        uint4 v0 = {0, 0, 0, 0}, v1 = {0, 0, 0, 0}, v2 = {0, 0, 0, 0}, v3 = {0, 0, 0, 0};
        if (gi >= 0) {
            const uint4* src = (const uint4*)(fin + (size_t)gi * 64) + ah * 4;
            v0 = src[0]; v1 = src[1]; v2 = src[2]; v3 = src[3];
        }
        {
            int sw = arow & 7;
            uint4* dst = As + arow * 8;
            dst[(ah * 4 + 0) ^ sw] = v0;
            dst[(ah * 4 + 1) ^ sw] = v1;
            dst[(ah * 4 + 2) ^ sw] = v2;
            dst[(ah * 4 + 3) ^ sw] = v3;
        }
        {
            const uint4* src = (const uint4*)(Wt + (size_t)k * 4096 + wrow * 64);
            int sw = wrow & 7;
            uint4* dst = Ws + wrow * 8;
            dst[wq ^ sw] = src[wq];
            dst[(wq + 4) ^ sw] = src[wq + 4];
        }
        __syncthreads();
        const s8v* Av = (const s8v*)As;
        const s8v* Wv = (const s8v*)Ws;
#pragma unroll
        for (int kb = 0; kb < 2; ++kb) {
            int g = kb * 4 + lg;
            s8v a0 = Av[rowA0 * 8 + (g ^ swA0)];
            s8v a1 = Av[rowA1 * 8 + (g ^ swA1)];
#pragma unroll
            for (int nf = 0; nf < 4; ++nf) {
                int col = nf * 16 + l15;
                s8v bf = Wv[col * 8 + (g ^ (col & 7))];
                acc[0][nf] = __builtin_amdgcn_mfma_f32_16x16x32_bf16(a0, bf, acc[0][nf], 0, 0, 0);
                acc[1][nf] = __builtin_amdgcn_mfma_f32_16x16x32_bf16(a1, bf, acc[1][nf], 0, 0, 0);
            }
        }
    }
    int base = rb + w * 32;
#pragma unroll
    for (int rf = 0; rf < 2; ++rf)
#pragma unroll
        for (int nf = 0; nf < 4; ++nf)
#pragma unroll
            for (int j = 0; j < 4; ++j) {
                int r = base + rf * 16 + lg * 4 + j;
                if (r < n) vout[(size_t)r * 64 + nf * 16 + l15] = acc[rf][nf][j];
            }
    if (EPI == 1) {
        __syncthreads();
        float* sp = (float*)As;
        int gidx = w * 4 + lg;
#pragma unroll
        for (int nf = 0; nf < 4; ++nf) {
            int col = nf * 16 + l15;
            float s = 0.f, s2 = 0.f;
#pragma unroll
            for (int rf = 0; rf < 2; ++rf)
#pragma unroll
                for (int j = 0; j < 4; ++j) {
                    int r = base + rf * 16 + lg * 4 + j;
                    if (r < n) {
                        float v = acc[rf][nf][j];
                        s += v;
                        s2 += v * v;
                    }
                }
            sp[gidx * 64 + col] = s;
            sp[1024 + gidx * 64 + col] = s2;
        }
        __syncthreads();
        if (t < 64) {
            float s = 0.f, s2 = 0.f;
#pragma unroll
            for (int i = 0; i < 16; ++i) {
                s += sp[i * 64 + t];
                s2 += sp[1024 + i * 64 + t];
            }
            atomicAdd(&stats_out[t], (double)s);
            atomicAdd(&stats_out[64 + t], (double)s2);
        }
    }
}

// ---------------- f16 = bf16(lrelu(bn(t3)) + feat) ----------------
__global__ __launch_bounds__(256) void addfeat_kernel(const float* __restrict__ t3, const double* __restrict__ stats,
                                                      const float* __restrict__ g, const float* __restrict__ b,
                                                      const float* __restrict__ feat, ushort* __restrict__ f16,
                                                      int n) {
    __shared__ float sb[128];
    bn_sb(stats, g, b, n, sb);
    long total4 = (long)n * 16;
    for (long i = (long)blockIdx.x * 256 + threadIdx.x; i < total4; i += (long)gridDim.x * 256) {
        int c0 = (int)(i & 15) * 4;
        float4 x = ((const float4*)t3)[i];
        float4 fz = ((const float4*)feat)[i];
        ushort4 u;
        u.x = f2bf(lrelu(x.x * sb[c0 + 0] + sb[64 + c0 + 0]) + fz.x);
        u.y = f2bf(lrelu(x.y * sb[c0 + 1] + sb[64 + c0 + 1]) + fz.y);
        u.z = f2bf(lrelu(x.z * sb[c0 + 2] + sb[64 + c0 + 2]) + fz.z);
        u.w = f2bf(lrelu(x.w * sb[c0 + 3] + sb[64 + c0 + 3]) + fz.w);
        ((ushort4*)f16)[i] = u;
    }
}

// ---------------- o16 = bf16(lrelu(bn(v))) ----------------
__global__ __launch_bounds__(256) void bnlrelu_tobf16_kernel(const float* __restrict__ v,
                                                             const double* __restrict__ stats,
                                                             const float* __restrict__ g, const float* __restrict__ b,
                                                             ushort* __restrict__ o16, int n) {
    __shared__ float sb[128];
    bn_sb(stats, g, b, n, sb);
    long total4 = (long)n * 16;
    for (long i = (long)blockIdx.x * 256 + threadIdx.x; i < total4; i += (long)gridDim.x * 256) {
        int c0 = (int)(i & 15) * 4;
        float4 x = ((const float4*)v)[i];
        ushort4 u;
        u.x = f2bf(lrelu(x.x * sb[c0 + 0] + sb[64 + c0 + 0]));
        u.y = f2bf(lrelu(x.y * sb[c0 + 1] + sb[64 + c0 + 1]));
        u.z = f2bf(lrelu(x.z * sb[c0 + 2] + sb[64 + c0 + 2]));
        u.w = f2bf(lrelu(x.w * sb[c0 + 3] + sb[64 + c0 + 3]));
        ((ushort4*)o16)[i] = u;
    }
}

// ---------------- out = lrelu(bn(w) + f16) ----------------
__global__ __launch_bounds__(256) void final_kernel(const float* __restrict__ w, const double* __restrict__ stats,
                                                    const float* __restrict__ g, const float* __restrict__ b,
                                                    const ushort* __restrict__ f16, float* __restrict__ out, int n) {
    __shared__ float sb[128];
    bn_sb(stats, g, b, n, sb);
    long total4 = (long)n * 16;
    for (long i = (long)blockIdx.x * 256 + threadIdx.x; i < total4; i += (long)gridDim.x * 256) {
        int c0 = (int)(i & 15) * 4;
        float4 x = ((const float4*)w)[i];
        ushort4 u = ((const ushort4*)f16)[i];
        float4 y;
        y.x = lrelu(x.x * sb[c0 + 0] + sb[64 + c0 + 0] + bf2f(u.x));
        y.y = lrelu(x.y * sb[c0 + 1] + sb[64 + c0 + 1] + bf2f(u.y));
        y.z = lrelu(x.z * sb[c0 + 2] + sb[64 + c0 + 2] + bf2f(u.z));
        y.w = lrelu(x.w * sb[c0 + 3] + sb[64 + c0 + 3] + bf2f(u.w));
        ((float4*)out)[i] = y;
    }
}

extern "C" void kernel_launch(void* const* d_in, const int* in_sizes, int n_in,
                              void* d_out, int out_size, void* d_ws, size_t ws_size,
                              hipStream_t stream) {
    const float* feat = (const float*)d_in[0];
    const float* lw_W = (const float*)d_in[1];
    const float* lw_g = (const float*)d_in[2];
    const float* lw_b = (const float*)d_in[3];
    const float* w_W = (const float*)d_in[4];
    const float* proj_W = (const float*)d_in[5];
    const float* proj_g = (const float*)d_in[6];
    const float* proj_b = (const float*)d_in[7];
    const float* adaptive_W = (const float*)d_in[8];
    const float* fuse_W = (const float*)d_in[9];
    const float* fuse_g = (const float*)d_in[10];
    const float* fuse_b = (const float*)d_in[11];
    const float* conv1_W = (const float*)d_in[12];
    const float* bn1_g = (const float*)d_in[13];
    const float* bn1_b = (const float*)d_in[14];
    const float* conv2_W = (const float*)d_in[15];
    const float* bn2_g = (const float*)d_in[16];
    const float* bn2_b = (const float*)d_in[17];
    const int* clusters = (const int*)d_in[18];
    const int* nbr = (const int*)d_in[19];

    const int n = in_sizes[0] / 64;

    char* ws = (char*)d_ws;
    size_t off = 0;
    auto alloc = [&](size_t bytes) -> size_t {
        size_t o = off;
        off = (off + bytes + 255) & ~(size_t)255;
        return o;
    };
    // zeroed region (tiny)
    size_t cnt_off = alloc((size_t)3 * KCL * 4);
    size_t stats_off = alloc((size_t)10 * 128 * 8);
    size_t gmax_off = alloc(16);
    size_t zbytes = off;
    // non-zeroed (fully overwritten each launch)
    size_t off_off = alloc((size_t)3 * KCL * 4);
    size_t cur_off = alloc((size_t)3 * KCL * 4);
    size_t perm_off = alloc((size_t)3 * n * 4);
    size_t mean_off = alloc((size_t)KCL * 64 * 4);
    size_t seg2_off = alloc((size_t)KCL * 64 * 4);
    size_t seg3_off = alloc((size_t)3 * KCL * 64 * 4);
    size_t mw_off = alloc((size_t)KCL * 64 * 4);
    size_t adp_off = alloc((size_t)n * 3 * 4);
    size_t bufA_off = alloc((size_t)n * 64 * 4);
    size_t bufB_off = alloc((size_t)n * 64 * 4);
    size_t feat16_off = alloc((size_t)n * 64 * 2);
    size_t fbuf16_off = alloc((size_t)n * 64 * 2);
    size_t cbuf16_off = alloc((size_t)n * 64 * 2);
    size_t wt64_off = alloc((size_t)64 * 4096 * 2);
    size_t wfT_off = alloc((size_t)8192 * 2);

    int* cnts = (int*)(ws + cnt_off);
    double* stats = (double*)(ws + stats_off);
    unsigned* gmax = (unsigned*)(ws + gmax_off);
    int* offs = (int*)(ws + off_off);
    int* cursor = (int*)(ws + cur_off);
    int* perm = (int*)(ws + perm_off);
    float* meanB = (float*)(ws + mean_off);
    float* seg2 = (float*)(ws + seg2_off);
    float* seg3 = (float*)(ws + seg3_off);
    float* MW = (float*)(ws + mw_off);
    float* adp = (float*)(ws + adp_off);
    float* bufA = (float*)(ws + bufA_off);
    float* bufB = (float*)(ws + bufB_off);
    ushort* feat16 = (ushort*)(ws + feat16_off);
    ushort* fbuf16 = (ushort*)(ws + fbuf16_off);
    ushort* cbuf16 = (ushort*)(ws + cbuf16_off);
    ushort* wt64 = (ushort*)(ws + wt64_off);
    ushort* wfT = (ushort*)(ws + wfT_off);
    float* outp = (float*)d_out;

    const ushort* lwW16 = wt64;
    const ushort* wW16 = wt64 + (size_t)3 * 4096;
    const ushort* projW16 = wt64 + (size_t)6 * 4096;
    const ushort* conv1W16 = wt64 + (size_t)10 * 4096;
    const ushort* conv2W16 = wt64 + (size_t)37 * 4096;

    hipMemsetAsync(d_ws, 0, zbytes, stream);

    const int GEMM_BLK = (n + 127) / 128;
    const int EW_BLK = 2048;

    prep_wt64<<<64, 256, 0, stream>>>(lw_W, w_W, proj_W, conv1_W, conv2_W, wt64);
    prep_fuse<<<1, 256, 0, stream>>>(fuse_W, wfT);
    cvt_bf16_kernel<<<EW_BLK, 256, 0, stream>>>(feat, feat16, (long)n * 16);
    adp_kernel<<<1024, 256, 0, stream>>>(feat, adaptive_W, adp, n);

    // cluster sort prep (all 3 levels)
    hist3_kernel<<<384, 256, 0, stream>>>(clusters, cnts, n);
    scan_kernel<<<3, 256, 0, stream>>>(cnts, offs, cursor, n);
    scatter_kernel<<<1024, 256, 0, stream>>>(clusters, cursor, perm, n);

    for (int i = 0; i < 3; ++i) {
        const int* clus = clusters + (size_t)i * n;
        const int* cnt_l = cnts + (size_t)i * KCL;
        const int* off_l = offs + (size_t)i * KCL;
        float* seg3_l = seg3 + (size_t)i * KCL * 64;
        double* stA = stats + (size_t)(2 * i + 0) * 128;
        double* stE = stats + (size_t)(2 * i + 1) * 128;

        // A = feat16 @ lw_W[i], + colstats
        gemm_mfma<0, 1><<<GEMM_BLK, 256, 0, stream>>>(feat16, lwW16 + (size_t)i * 4096, bufA, n, n,
                                                      nullptr, nullptr, nullptr, stA,
                                                      nullptr, nullptr, nullptr);
        // meanB[c] = mean over cluster of lrelu(bn(A))
        reduce_mean_kernel<<<KCL, 256, 0, stream>>>(bufA, stA, lw_g + i * 64, lw_b + i * 64, n,
                                                    cnt_l, off_l, perm, meanB);
        // MW = meanB @ w_W[i]
        gemm_mfma<1, 0><<<(KCL + 127) / 128, 256, 0, stream>>>(meanB, wW16 + (size_t)i * 4096, MW, KCL, KCL,
                                                               nullptr, nullptr, nullptr, nullptr,
                                                               nullptr, nullptr, nullptr);
        // C = bnlrelu(A) @ w_W[i] - MW[c], + global max
        gemm_mfma<2, 2><<<GEMM_BLK, 256, 0, stream>>>(bufA, wW16 + (size_t)i * 4096, bufB, n, n,
                                                      stA, lw_g + i * 64, lw_b + i * 64, nullptr,
                                                      MW, clus, gmax + i);
        // seg2[c] = sum exp(C - gmax)
        reduce_exp_kernel<<<KCL, 256, 0, stream>>>(bufB, gmax + i, cnt_l, off_l, perm, seg2);
        // E = feat16 @ proj_W[i], + colstats
        gemm_mfma<0, 1><<<GEMM_BLK, 256, 0, stream>>>(feat16, projW16 + (size_t)i * 4096, bufA, n, n,
                                                      nullptr, nullptr, nullptr, stE,
                                                      nullptr, nullptr, nullptr);
        // seg3[c] = sum lrelu(bn(E)) * exp(C-gmax) / (seg2[c]+1e-6)
        reduce_pf_kernel<<<KCL, 256, 0, stream>>>(bufA, stE, proj_g + i * 64, proj_b + i * 64, n,
                                                  bufB, gmax + i, seg2, cnt_l, off_l, perm, seg3_l);
    }

    // P3 = feat16 @ proj_W[3], + colstats
    gemm_mfma<0, 1><<<GEMM_BLK, 256, 0, stream>>>(feat16, projW16 + (size_t)3 * 4096, bufA, n, n,
                                                  nullptr, nullptr, nullptr, stats + 6 * 128,
                                                  nullptr, nullptr, nullptr);
    // t3 = [bnlrelu(P3) | blend(adp,seg3)] @ fuse_W, + colstats
    fuse_mfma<<<GEMM_BLK, 256, 0, stream>>>(bufA, stats + 6 * 128, proj_g + 192, proj_b + 192, n,
                                            adp, clusters,
                                            seg3, seg3 + (size_t)KCL * 64, seg3 + (size_t)2 * KCL * 64,
                                            wfT, bufB, stats + 7 * 128);
    // f = lrelu(bn(t3)) + feat  (bf16)
    addfeat_kernel<<<EW_BLK, 256, 0, stream>>>(bufB, stats + 7 * 128, fuse_g, fuse_b, feat, fbuf16, n);

    // conv1 (+stats) -> d_out scratch, then bn1+lrelu -> bf16
    subm_conv_mfma_kernel<1><<<GEMM_BLK, 256, 0, stream>>>(fbuf16, nbr, conv1W16, outp, n, stats + 8 * 128);
    bnlrelu_tobf16_kernel<<<EW_BLK, 256, 0, stream>>>(outp, stats + 8 * 128, bn1_g, bn1_b, cbuf16, n);

    // conv2 (+stats) -> bufA, then out = lrelu(bn2 + f)
    subm_conv_mfma_kernel<1><<<GEMM_BLK, 256, 0, stream>>>(cbuf16, nbr, conv2W16, bufA, n, stats + 9 * 128);
    final_kernel<<<EW_BLK, 256, 0, stream>>>(bufA, stats + 9 * 128, bn2_g, bn2_b, fbuf16, outp, n);
}

// Round 5
// 647.721 us; speedup vs baseline: 2.9398x; 1.2966x over previous
//
#include <hip/hip_runtime.h>
#include <hip/hip_bf16.h>
#include <math.h>

#define KCL 2048
#define LRELU_NEG 0.01f
#define EPSBN 1e-5f

using s8v = __attribute__((ext_vector_type(8))) short;   // 8 bf16 (4 VGPRs)
using f4v = __attribute__((ext_vector_type(4))) float;   // MFMA accumulator

union U8 { ushort u[8]; uint4 v; };

__device__ __forceinline__ float lrelu(float x) { return x > 0.f ? x : LRELU_NEG * x; }
__device__ __forceinline__ ushort f2bf(float f) {
    __hip_bfloat16 h = __float2bfloat16(f);
    return *reinterpret_cast<ushort*>(&h);
}
__device__ __forceinline__ float bf2f(ushort u) { return __uint_as_float(((unsigned)u) << 16); }

// monotonic float->uint encoding for atomicMax over mixed-sign floats
__device__ __forceinline__ unsigned encf(float f) {
    unsigned u = __float_as_uint(f);
    return (u & 0x80000000u) ? ~u : (u | 0x80000000u);
}
__device__ __forceinline__ float decf(unsigned u) {
    return __uint_as_float((u & 0x80000000u) ? (u & 0x7fffffffu) : ~u);
}

// finalize BN stats into LDS scale/bias: y = x*sb[col] + sb[64+col]
__device__ __forceinline__ void bn_sb(const double* __restrict__ stats, const float* __restrict__ g,
                                      const float* __restrict__ b, int n, float* sb) {
    int t = threadIdx.x;
    if (t < 64) {
        float mean = (float)(stats[t] / n);
        float ex2 = (float)(stats[64 + t] / n);
        float var = fmaxf(ex2 - mean * mean, 0.f);
        float rstd = rsqrtf(var + EPSBN);
        float sc = rstd * g[t];
        sb[t] = sc;
        sb[64 + t] = b[t] - mean * sc;
    }
    __syncthreads();
}

// ---------------- shared MFMA helpers ----------------
__device__ __forceinline__ void mfma_tile(const uint4* As, const uint4* Ws, int rowA0, int rowA1,
                                          int swA0, int swA1, int l15, int lg, f4v acc[2][4]) {
    const s8v* Av = (const s8v*)As;
    const s8v* Wv = (const s8v*)Ws;
#pragma unroll
    for (int kb = 0; kb < 2; ++kb) {
        int gch = kb * 4 + lg;
        s8v a0 = Av[rowA0 * 8 + (gch ^ swA0)];
        s8v a1 = Av[rowA1 * 8 + (gch ^ swA1)];
#pragma unroll
        for (int nf = 0; nf < 4; ++nf) {
            int col = nf * 16 + l15;
            s8v bf = Wv[col * 8 + (gch ^ (col & 7))];
            acc[0][nf] = __builtin_amdgcn_mfma_f32_16x16x32_bf16(a0, bf, acc[0][nf], 0, 0, 0);
            acc[1][nf] = __builtin_amdgcn_mfma_f32_16x16x32_bf16(a1, bf, acc[1][nf], 0, 0, 0);
        }
    }
}

__device__ __forceinline__ void stage_w(const ushort* Wmat, uint4* Ws, int wrow, int wq) {
    const uint4* src = (const uint4*)(Wmat + (size_t)wrow * 64);
    int sw = wrow & 7;
    Ws[wrow * 8 + (wq ^ sw)] = src[wq];
    Ws[wrow * 8 + ((wq + 4) ^ sw)] = src[wq + 4];
}

__device__ __forceinline__ void stage_a_bf16(const ushort* S, uint4* As, int row, int n, int arow, int ah) {
    uint4 c0 = {0, 0, 0, 0}, c1 = c0, c2 = c0, c3 = c0;
    if (row < n) {
        const uint4* s = (const uint4*)(S + (size_t)row * 64) + ah * 4;
        c0 = s[0]; c1 = s[1]; c2 = s[2]; c3 = s[3];
    }
    int sw = arow & 7;
    uint4* dst = As + arow * 8;
    dst[(ah * 4 + 0) ^ sw] = c0;
    dst[(ah * 4 + 1) ^ sw] = c1;
    dst[(ah * 4 + 2) ^ sw] = c2;
    dst[(ah * 4 + 3) ^ sw] = c3;
}

__device__ __forceinline__ void stage_a_vals(const float* vals, uint4* As, int arow, int ah) {
    int sw = arow & 7;
    uint4* dst = As + arow * 8;
#pragma unroll
    for (int c = 0; c < 4; ++c) {
        U8 u;
#pragma unroll
        for (int e = 0; e < 8; ++e) u.u[e] = f2bf(vals[c * 8 + e]);
        dst[(ah * 4 + c) ^ sw] = u.v;
    }
}

// ---------------- weight prep: 64 matrices of 64x64, transposed -> bf16 ----------------
__global__ __launch_bounds__(256) void prep_wt64(const float* __restrict__ lw, const float* __restrict__ wW,
                                                 const float* __restrict__ proj, const float* __restrict__ c1,
                                                 const float* __restrict__ c2, ushort* __restrict__ wt) {
    int bk = blockIdx.x;
    const float* W;
    if (bk < 3) W = lw + (size_t)bk * 4096;
    else if (bk < 6) W = wW + (size_t)(bk - 3) * 4096;
    else if (bk < 10) W = proj + (size_t)(bk - 6) * 4096;
    else if (bk < 37) W = c1 + (size_t)(bk - 10) * 4096;
    else W = c2 + (size_t)(bk - 37) * 4096;
    ushort* o = wt + (size_t)bk * 4096;
    for (int i = threadIdx.x; i < 4096; i += 256) {
        int kk = i >> 6, cc = i & 63;
        o[cc * 64 + kk] = f2bf(W[i]);
    }
}

__global__ __launch_bounds__(256) void prep_fuse(const float* __restrict__ Wf, ushort* __restrict__ o) {
    for (int i = threadIdx.x; i < 8192; i += 256) {
        int kk = i >> 6, cc = i & 63;
        o[cc * 128 + kk] = f2bf(Wf[i]);
    }
}

// ---------------- fp32 -> bf16 bulk convert ----------------
__global__ __launch_bounds__(256) void cvt_bf16_kernel(const float* __restrict__ in, ushort* __restrict__ o,
                                                       long n4) {
    for (long i = (long)blockIdx.x * 256 + threadIdx.x; i < n4; i += (long)gridDim.x * 256) {
        float4 x = ((const float4*)in)[i];
        ushort4 u;
        u.x = f2bf(x.x); u.y = f2bf(x.y); u.z = f2bf(x.z); u.w = f2bf(x.w);
        ((ushort4*)o)[i] = u;
    }
}

// ---------------- cluster histogram, all 3 levels ----------------
__global__ __launch_bounds__(256) void hist3_kernel(const int* __restrict__ clusters, int* __restrict__ cnt,
                                                    int n) {
    __shared__ int h[KCL];
    int l = blockIdx.x % 3;
    int nb = gridDim.x / 3, bi = blockIdx.x / 3;
    for (int i = threadIdx.x; i < KCL; i += 256) h[i] = 0;
    __syncthreads();
    const int* cl = clusters + (size_t)l * n;
    for (long i = (long)bi * 256 + threadIdx.x; i < n; i += (long)nb * 256)
        atomicAdd(&h[cl[i]], 1);
    __syncthreads();
    for (int i = threadIdx.x; i < KCL; i += 256) {
        int v = h[i];
        if (v) atomicAdd(&cnt[l * KCL + i], v);
    }
}

// ---------------- exclusive scan of counts per level -> absolute offsets + cursor ----------------
__global__ __launch_bounds__(256) void scan_kernel(const int* __restrict__ cnt, int* __restrict__ off,
                                                   int* __restrict__ cursor, int n) {
    int l = blockIdx.x;
    const int* c = cnt + l * KCL;
    __shared__ int part[256];
    __shared__ int pref[256];
    int t = threadIdx.x;
    int base = t * 8;
    int v[8];
    int s = 0;
#pragma unroll
    for (int j = 0; j < 8; ++j) { v[j] = c[base + j]; s += v[j]; }
    part[t] = s;
    __syncthreads();
    if (t == 0) {
        int acc = 0;
        for (int i = 0; i < 256; ++i) { pref[i] = acc; acc += part[i]; }
    }
    __syncthreads();
    int acc = pref[t] + l * n;
#pragma unroll
    for (int j = 0; j < 8; ++j) {
        off[l * KCL + base + j] = acc;
        cursor[l * KCL + base + j] = acc;
        acc += v[j];
    }
}

// ---------------- scatter rows into cluster-sorted perm ----------------
__global__ __launch_bounds__(256) void scatter_kernel(const int* __restrict__ clusters, int* __restrict__ cursor,
                                                      int* __restrict__ perm, int n) {
    long n3 = (long)n * 3;
    for (long i = (long)blockIdx.x * 256 + threadIdx.x; i < n3; i += (long)gridDim.x * 256) {
        int l = (i >= n) + (i >= 2 * (long)n);
        int c = clusters[i];
        int pos = atomicAdd(&cursor[l * KCL + c], 1);
        perm[pos] = (int)(i - (long)l * n);
    }
}

// ---------------- adaptive weights from bf16 feat ----------------
__global__ __launch_bounds__(256) void adp_kernel(const ushort* __restrict__ feat16, const float* __restrict__ aW,
                                                  float* __restrict__ adp, int n) {
    __shared__ float w[192];
    for (int i = threadIdx.x; i < 192; i += 256) w[i] = aW[i];
    __syncthreads();
    for (long row = (long)blockIdx.x * 256 + threadIdx.x; row < n; row += (long)gridDim.x * 256) {
        const ushort4* fr = (const ushort4*)(feat16 + row * 64);
        float l0 = 0.f, l1 = 0.f, l2 = 0.f;
#pragma unroll
        for (int q = 0; q < 16; ++q) {
            ushort4 uv = fr[q];
            float x0 = bf2f(uv.x), x1 = bf2f(uv.y), x2 = bf2f(uv.z), x3 = bf2f(uv.w);
            int k = q * 4;
            l0 += x0 * w[k * 3 + 0] + x1 * w[k * 3 + 3] + x2 * w[k * 3 + 6] + x3 * w[k * 3 + 9];
            l1 += x0 * w[k * 3 + 1] + x1 * w[k * 3 + 4] + x2 * w[k * 3 + 7] + x3 * w[k * 3 + 10];
            l2 += x0 * w[k * 3 + 2] + x1 * w[k * 3 + 5] + x2 * w[k * 3 + 8] + x3 * w[k * 3 + 11];
        }
        float m = fmaxf(l0, fmaxf(l1, l2));
        float e0 = expf(l0 - m), e1 = expf(l1 - m), e2 = expf(l2 - m);
        float inv = 1.f / (e0 + e1 + e2);
        adp[row * 3 + 0] = e0 * inv;
        adp[row * 3 + 1] = e1 * inv;
        adp[row * 3 + 2] = e2 * inv;
    }
}

// ================= mega GEMM: A_j = feat16 @ lw_j, j=0..2, bf16 out + stats(2j) =================
__global__ __launch_bounds__(256) void lw3_gemm(const ushort* __restrict__ feat16, const ushort* __restrict__ lwW16,
                                                ushort* __restrict__ A3, int n, double* __restrict__ stats) {
    __shared__ uint4 As[128 * 8];
    __shared__ uint4 Ws[64 * 8];
    __shared__ float red[512];
    int t = threadIdx.x, lane = t & 63, w = t >> 6;
    int rb = blockIdx.x * 128;
    int arow = t >> 1, ah = t & 1;
    int wrow = t >> 2, wq = t & 3;
    const int l15 = lane & 15, lg = lane >> 4;
    int rowA0 = w * 32 + l15, rowA1 = rowA0 + 16;
    int swA0 = rowA0 & 7, swA1 = rowA1 & 7;
    int base = rb + w * 32;

    stage_a_bf16(feat16, As, rb + arow, n, arow, ah);

    for (int j = 0; j < 3; ++j) {
        stage_w(lwW16 + (size_t)j * 4096, Ws, wrow, wq);
        __syncthreads();
        f4v acc[2][4];
#pragma unroll
        for (int rf = 0; rf < 2; ++rf)
#pragma unroll
            for (int nf = 0; nf < 4; ++nf)
#pragma unroll
                for (int q = 0; q < 4; ++q) acc[rf][nf][q] = 0.f;
        mfma_tile(As, Ws, rowA0, rowA1, swA0, swA1, l15, lg, acc);
        ushort* out = A3 + (size_t)j * n * 64;
#pragma unroll
        for (int rf = 0; rf < 2; ++rf)
#pragma unroll
            for (int nf = 0; nf < 4; ++nf)
#pragma unroll
                for (int q = 0; q < 4; ++q) {
                    int r = base + rf * 16 + lg * 4 + q;
                    if (r < n) out[(size_t)r * 64 + nf * 16 + l15] = f2bf(acc[rf][nf][q]);
                }
        // stats: shuffle over lg, then LDS over waves
#pragma unroll
        for (int nf = 0; nf < 4; ++nf) {
            float s = 0.f, s2 = 0.f;
#pragma unroll
            for (int rf = 0; rf < 2; ++rf)
#pragma unroll
                for (int q = 0; q < 4; ++q) {
                    int r = base + rf * 16 + lg * 4 + q;
                    if (r < n) {
                        float v = acc[rf][nf][q];
                        s += v;
                        s2 += v * v;
                    }
                }
            s += __shfl_xor(s, 16); s += __shfl_xor(s, 32);
            s2 += __shfl_xor(s2, 16); s2 += __shfl_xor(s2, 32);
            if (lg == 0) {
                red[w * 64 + nf * 16 + l15] = s;
                red[256 + w * 64 + nf * 16 + l15] = s2;
            }
        }
        __syncthreads();
        if (t < 64) {
            float s = red[t] + red[64 + t] + red[128 + t] + red[192 + t];
            float s2 = red[256 + t] + red[320 + t] + red[384 + t] + red[448 + t];
            double* st = stats + (size_t)(2 * j) * 128;
            atomicAdd(&st[t], (double)s);
            atomicAdd(&st[64 + t], (double)s2);
        }
    }
}

// ================= generic (n,64)@(64,64): bf16 in, bf16 out + stats =================
__global__ __launch_bounds__(256) void gemm_stats_bf16out(const ushort* __restrict__ src,
                                                          const ushort* __restrict__ Wt,
                                                          ushort* __restrict__ out, int n,
                                                          double* __restrict__ stats_out) {
    __shared__ uint4 As[128 * 8];
    __shared__ uint4 Ws[64 * 8];
    int t = threadIdx.x, lane = t & 63, w = t >> 6;
    int rb = blockIdx.x * 128;
    int arow = t >> 1, ah = t & 1;
    int wrow = t >> 2, wq = t & 3;
    const int l15 = lane & 15, lg = lane >> 4;
    stage_w(Wt, Ws, wrow, wq);
    stage_a_bf16(src, As, rb + arow, n, arow, ah);
    __syncthreads();
    f4v acc[2][4];
#pragma unroll
    for (int rf = 0; rf < 2; ++rf)
#pragma unroll
        for (int nf = 0; nf < 4; ++nf)
#pragma unroll
            for (int q = 0; q < 4; ++q) acc[rf][nf][q] = 0.f;
    int rowA0 = w * 32 + l15, rowA1 = rowA0 + 16;
    mfma_tile(As, Ws, rowA0, rowA1, rowA0 & 7, rowA1 & 7, l15, lg, acc);
    int base = rb + w * 32;
#pragma unroll
    for (int rf = 0; rf < 2; ++rf)
#pragma unroll
        for (int nf = 0; nf < 4; ++nf)
#pragma unroll
            for (int q = 0; q < 4; ++q) {
                int r = base + rf * 16 + lg * 4 + q;
                if (r < n) out[(size_t)r * 64 + nf * 16 + l15] = f2bf(acc[rf][nf][q]);
            }
    __syncthreads();
    float* sp = (float*)As;
    int gidx = w * 4 + lg;
#pragma unroll
    for (int nf = 0; nf < 4; ++nf) {
        int col = nf * 16 + l15;
        float s = 0.f, s2 = 0.f;
#pragma unroll
        for (int rf = 0; rf < 2; ++rf)
#pragma unroll
            for (int q = 0; q < 4; ++q) {
                int r = base + rf * 16 + lg * 4 + q;
                if (r < n) {
                    float v = acc[rf][nf][q];
                    s += v;
                    s2 += v * v;
                }
            }
        sp[gidx * 64 + col] = s;
        sp[1024 + gidx * 64 + col] = s2;
    }
    __syncthreads();
    if (t < 64) {
        float s = 0.f, s2 = 0.f;
#pragma unroll
        for (int i = 0; i < 16; ++i) {
            s += sp[i * 64 + t];
            s2 += sp[1024 + i * 64 + t];
        }
        atomicAdd(&stats_out[t], (double)s);
        atomicAdd(&stats_out[64 + t], (double)s2);
    }
}

// ================= meanB for all 3 levels (block = (level, cluster)) =================
__global__ __launch_bounds__(256) void reduce_mean3_kernel(const ushort* __restrict__ A3,
                                                           const double* __restrict__ stats,
                                                           const float* __restrict__ lw_g,
                                                           const float* __restrict__ lw_b, int n,
                                                           const int* __restrict__ cnts, const int* __restrict__ offs,
                                                           const int* __restrict__ perm,
                                                           float* __restrict__ meanB3) {
    int l = blockIdx.x >> 11, c = blockIdx.x & (KCL - 1);
    const ushort* A = A3 + (size_t)l * n * 64;
    __shared__ float sb[128];
    bn_sb(stats + (size_t)(2 * l) * 128, lw_g + l * 64, lw_b + l * 64, n, sb);
    int t = threadIdx.x, col = t & 63, rg = t >> 6;
    int o = offs[l * KCL + c], m = cnts[l * KCL + c];
    float acc = 0.f;
    float sc = sb[col], bi = sb[64 + col];
    for (int j = rg; j < m; j += 4) {
        int row = perm[o + j];
        acc += lrelu(bf2f(A[(size_t)row * 64 + col]) * sc + bi);
    }
    __shared__ float red[256];
    red[t] = acc;
    __syncthreads();
    if (t < 64) {
        float s = red[t] + red[t + 64] + red[t + 128] + red[t + 192];
        float cf = (float)m;
        if (cf < 1.f) cf = 1.f;
        meanB3[(size_t)l * KCL * 64 + (size_t)c * 64 + col] = s / cf;
    }
}

// ================= MW for all 3 levels: meanB_l @ wW_l (2048 rows each) =================
__global__ __launch_bounds__(256) void mw3_gemm(const float* __restrict__ meanB3, const ushort* __restrict__ wW16,
                                                float* __restrict__ MW3) {
    __shared__ uint4 As[128 * 8];
    __shared__ uint4 Ws[64 * 8];
    int l = blockIdx.x >> 4, b = blockIdx.x & 15;
    const float* src = meanB3 + (size_t)l * KCL * 64;
    float* out = MW3 + (size_t)l * KCL * 64;
    int t = threadIdx.x, lane = t & 63, w = t >> 6;
    int rb = b * 128;
    int arow = t >> 1, ah = t & 1;
    int wrow = t >> 2, wq = t & 3;
    const int l15 = lane & 15, lg = lane >> 4;
    stage_w(wW16 + (size_t)l * 4096, Ws, wrow, wq);
    {
        float vals[32];
        const float4* s = (const float4*)(src + (size_t)(rb + arow) * 64 + ah * 32);
#pragma unroll
        for (int q = 0; q < 8; ++q) {
            float4 x = s[q];
            vals[q * 4 + 0] = x.x; vals[q * 4 + 1] = x.y;
            vals[q * 4 + 2] = x.z; vals[q * 4 + 3] = x.w;
        }
        stage_a_vals(vals, As, arow, ah);
    }
    __syncthreads();
    f4v acc[2][4];
#pragma unroll
    for (int rf = 0; rf < 2; ++rf)
#pragma unroll
        for (int nf = 0; nf < 4; ++nf)
#pragma unroll
            for (int q = 0; q < 4; ++q) acc[rf][nf][q] = 0.f;
    int rowA0 = w * 32 + l15, rowA1 = rowA0 + 16;
    mfma_tile(As, Ws, rowA0, rowA1, rowA0 & 7, rowA1 & 7, l15, lg, acc);
    int base = rb + w * 32;
#pragma unroll
    for (int rf = 0; rf < 2; ++rf)
#pragma unroll
        for (int nf = 0; nf < 4; ++nf)
#pragma unroll
            for (int q = 0; q < 4; ++q) {
                int r = base + rf * 16 + lg * 4 + q;
                out[(size_t)r * 64 + nf * 16 + l15] = acc[rf][nf][q];
            }
}

// ================= C_l = bnlrelu(A_l) @ wW_l - MW_l[clus], all levels, bf16 out + gmax =================
__global__ __launch_bounds__(256) void cgemm3(const ushort* __restrict__ A3, const ushort* __restrict__ wW16,
                                              const float* __restrict__ MW3, const int* __restrict__ clusters,
                                              const double* __restrict__ stats, const float* __restrict__ lw_g,
                                              const float* __restrict__ lw_b, ushort* __restrict__ C3,
                                              unsigned* __restrict__ gmax, int n, int nb) {
    __shared__ uint4 As[128 * 8];
    __shared__ uint4 Ws[64 * 8];
    __shared__ float sb[128];
    int l = blockIdx.x / nb, b = blockIdx.x % nb;
    const ushort* A = A3 + (size_t)l * n * 64;
    ushort* C = C3 + (size_t)l * n * 64;
    const float* MW = MW3 + (size_t)l * KCL * 64;
    const int* clus = clusters + (size_t)l * n;
    int t = threadIdx.x, lane = t & 63, w = t >> 6;
    int rb = b * 128;
    int arow = t >> 1, ah = t & 1;
    int wrow = t >> 2, wq = t & 3;
    const int l15 = lane & 15, lg = lane >> 4;

    bn_sb(stats + (size_t)(2 * l) * 128, lw_g + l * 64, lw_b + l * 64, n, sb);
    stage_w(wW16 + (size_t)l * 4096, Ws, wrow, wq);
    {
        int row = rb + arow;
        float vals[32];
        if (row < n) {
            const U8* s8p = (const U8*)(A + (size_t)row * 64 + ah * 32);
#pragma unroll
            for (int c = 0; c < 4; ++c) {
                U8 u = s8p[c];
#pragma unroll
                for (int e = 0; e < 8; ++e) {
                    int col = ah * 32 + c * 8 + e;
                    vals[c * 8 + e] = lrelu(bf2f(u.u[e]) * sb[col] + sb[64 + col]);
                }
            }
        } else {
#pragma unroll
            for (int i = 0; i < 32; ++i) vals[i] = 0.f;
        }
        stage_a_vals(vals, As, arow, ah);
    }
    __syncthreads();
    f4v acc[2][4];
#pragma unroll
    for (int rf = 0; rf < 2; ++rf)
#pragma unroll
        for (int nf = 0; nf < 4; ++nf)
#pragma unroll
            for (int q = 0; q < 4; ++q) acc[rf][nf][q] = 0.f;
    int rowA0 = w * 32 + l15, rowA1 = rowA0 + 16;
    mfma_tile(As, Ws, rowA0, rowA1, rowA0 & 7, rowA1 & 7, l15, lg, acc);
    int base = rb + w * 32;
    float m = -INFINITY;
#pragma unroll
    for (int rf = 0; rf < 2; ++rf)
#pragma unroll
        for (int q = 0; q < 4; ++q) {
            int r = base + rf * 16 + lg * 4 + q;
            if (r < n) {
                int c = clus[r];
                const float* mwr = MW + (size_t)c * 64;
#pragma unroll
                for (int nf = 0; nf < 4; ++nf) {
                    int col = nf * 16 + l15;
                    float v = acc[rf][nf][q] - mwr[col];
                    C[(size_t)r * 64 + col] = f2bf(v);
                    m = fmaxf(m, v);
                }
            }
        }
    __syncthreads();
    float* sp = (float*)As;
    sp[t] = m;
    __syncthreads();
    for (int s = 128; s > 0; s >>= 1) {
        if (t < s) sp[t] = fmaxf(sp[t], sp[t + s]);
        __syncthreads();
    }
    if (t == 0) atomicMax(&gmax[l], encf(sp[0]));
}

// ================= fused per-cluster softmax pool: seg3[c] = Σ pf·d / (Σ d + 1e-6) =================
__global__ __launch_bounds__(256) void reduce_expf_kernel(const ushort* __restrict__ C, const ushort* __restrict__ E,
                                                          const double* __restrict__ stats,
                                                          const float* __restrict__ g, const float* __restrict__ b,
                                                          int n, const unsigned* __restrict__ gmaxp,
                                                          const int* __restrict__ cnt, const int* __restrict__ off,
                                                          const int* __restrict__ perm, float* __restrict__ seg3) {
    __shared__ float sb[128];
    bn_sb(stats, g, b, n, sb);
    int c = blockIdx.x;
    int t = threadIdx.x, col = t & 63, rg = t >> 6;
    float gm = decf(*gmaxp);
    int o = off[c], m = cnt[c];
    float accd = 0.f, accn = 0.f;
    float sc = sb[col], bi = sb[64 + col];
    for (int j = rg; j < m; j += 4) {
        int row = perm[o + j];
        float d = expf(bf2f(C[(size_t)row * 64 + col]) - gm);
        float pf = lrelu(bf2f(E[(size_t)row * 64 + col]) * sc + bi);
        accd += d;
        accn += pf * d;
    }
    __shared__ float redd[256], redn[256];
    redd[t] = accd;
    redn[t] = accn;
    __syncthreads();
    if (t < 64) {
        float sd = redd[t] + redd[t + 64] + redd[t + 128] + redd[t + 192];
        float sn = redn[t] + redn[t + 64] + redn[t + 128] + redn[t + 192];
        seg3[(size_t)c * 64 + col] = sn / (sd + 1e-6f);
    }
}

// ================= fuse GEMM: t3 = [bnlrelu(P3) | blend] @ Wf(128x64), bf16 out + stats =================
__global__ __launch_bounds__(256) void fuse_mfma(const ushort* __restrict__ P3, const double* __restrict__ statsP,
                                                 const float* __restrict__ gg, const float* __restrict__ bb, int n,
                                                 const float* __restrict__ adp, const int* __restrict__ clusters,
                                                 const float* __restrict__ s3_0, const float* __restrict__ s3_1,
                                                 const float* __restrict__ s3_2, const ushort* __restrict__ WfT,
                                                 ushort* __restrict__ out, double* __restrict__ stats_out) {
    __shared__ uint4 As[128 * 8];
    __shared__ uint4 Ws[64 * 8];
    __shared__ float sb[128];
    int t = threadIdx.x, lane = t & 63, w = t >> 6;
    int rb = blockIdx.x * 128;
    int arow = t >> 1, ah = t & 1;
    int wrow = t >> 2, wq = t & 3;
    const int l15 = lane & 15, lg = lane >> 4;

    bn_sb(statsP, gg, bb, n, sb);

    f4v acc[2][4];
#pragma unroll
    for (int rf = 0; rf < 2; ++rf)
#pragma unroll
        for (int nf = 0; nf < 4; ++nf)
#pragma unroll
            for (int q = 0; q < 4; ++q) acc[rf][nf][q] = 0.f;

    int rowA0 = w * 32 + l15, rowA1 = rowA0 + 16;
    int row = rb + arow;

    for (int p = 0; p < 2; ++p) {
        if (p) __syncthreads();
        float vals[32];
        if (row < n) {
            if (p == 0) {
                const U8* s8p = (const U8*)(P3 + (size_t)row * 64 + ah * 32);
#pragma unroll
                for (int c = 0; c < 4; ++c) {
                    U8 u = s8p[c];
#pragma unroll
                    for (int e = 0; e < 8; ++e) {
                        int col = ah * 32 + c * 8 + e;
                        vals[c * 8 + e] = lrelu(bf2f(u.u[e]) * sb[col] + sb[64 + col]);
                    }
                }
            } else {
                float a0 = adp[(size_t)row * 3 + 0], a1 = adp[(size_t)row * 3 + 1], a2 = adp[(size_t)row * 3 + 2];
                const float* r0 = s3_0 + (size_t)clusters[row] * 64 + ah * 32;
                const float* r1 = s3_1 + (size_t)clusters[(size_t)n + row] * 64 + ah * 32;
                const float* r2 = s3_2 + (size_t)clusters[2 * (size_t)n + row] * 64 + ah * 32;
#pragma unroll
                for (int i = 0; i < 32; ++i) vals[i] = a0 * r0[i] + a1 * r1[i] + a2 * r2[i];
            }
        } else {
#pragma unroll
            for (int i = 0; i < 32; ++i) vals[i] = 0.f;
        }
        stage_a_vals(vals, As, arow, ah);
        {
            const uint4* srcw = (const uint4*)(WfT + (size_t)wrow * 128);
            int sw = wrow & 7;
            uint4* dst = Ws + wrow * 8;
            dst[wq ^ sw] = srcw[p * 8 + wq];
            dst[(wq + 4) ^ sw] = srcw[p * 8 + wq + 4];
        }
        __syncthreads();
        mfma_tile(As, Ws, rowA0, rowA1, rowA0 & 7, rowA1 & 7, l15, lg, acc);
    }
    int base = rb + w * 32;
#pragma unroll
    for (int rf = 0; rf < 2; ++rf)
#pragma unroll
        for (int nf = 0; nf < 4; ++nf)
#pragma unroll
            for (int q = 0; q < 4; ++q) {
                int r = base + rf * 16 + lg * 4 + q;
                if (r < n) out[(size_t)r * 64 + nf * 16 + l15] = f2bf(acc[rf][nf][q]);
            }
    __syncthreads();
    float* sp = (float*)As;
    int gidx = w * 4 + lg;
#pragma unroll
    for (int nf = 0; nf < 4; ++nf) {
        int col = nf * 16 + l15;
        float s = 0.f, s2 = 0.f;
#pragma unroll
        for (int rf = 0; rf < 2; ++rf)
#pragma unroll
            for (int q = 0; q < 4; ++q) {
                int r = base + rf * 16 + lg * 4 + q;
                if (r < n) {
                    float v = acc[rf][nf][q];
                    s += v;
                    s2 += v * v;
                }
            }
        sp[gidx * 64 + col] = s;
        sp[1024 + gidx * 64 + col] = s2;
    }
    __syncthreads();
    if (t < 64) {
        float s = 0.f, s2 = 0.f;
#pragma unroll
        for (int i = 0; i < 16; ++i) {
            s += sp[i * 64 + t];
            s2 += sp[1024 + i * 64 + t];
        }
        atomicAdd(&stats_out[t], (double)s);
        atomicAdd(&stats_out[64 + t], (double)s2);
    }
}

// ================= submanifold conv, double-buffered, bf16 in/out + stats =================
__global__ __launch_bounds__(256) void subm_conv_db(const ushort* __restrict__ fin, const int* __restrict__ nbr,
                                                    const ushort* __restrict__ Wt, ushort* __restrict__ vout,
                                                    int n, double* __restrict__ stats_out) {
    __shared__ uint4 As[2][128 * 8];
    __shared__ uint4 Ws[2][64 * 8];
    int t = threadIdx.x;
    int lane = t & 63, w = t >> 6;
    int rb = blockIdx.x * 128;
    int arow = t >> 1, ah = t & 1;
    int wrow = t >> 2, wq = t & 3;
    const int l15 = lane & 15, lg = lane >> 4;
    int rowA0 = w * 32 + l15, rowA1 = rowA0 + 16;
    int swA0 = rowA0 & 7, swA1 = rowA1 & 7;
    const bool rowok = (rb + arow) < n;
    const int swa = arow & 7, sww = wrow & 7;

    f4v acc[2][4];
#pragma unroll
    for (int rf = 0; rf < 2; ++rf)
#pragma unroll
        for (int nf = 0; nf < 4; ++nf)
#pragma unroll
            for (int q = 0; q < 4; ++q) acc[rf][nf][q] = 0.f;

    // prologue: k=0 into buf0, prefetch nbr for k=1
    {
        int gi = rowok ? nbr[rb + arow] : -1;
        uint4 v0 = {0, 0, 0, 0}, v1 = v0, v2 = v0, v3 = v0;
        if (gi >= 0) {
            const uint4* src = (const uint4*)(fin + (size_t)gi * 64) + ah * 4;
            v0 = src[0]; v1 = src[1]; v2 = src[2]; v3 = src[3];
        }
        uint4* dst = As[0] + arow * 8;
        dst[(ah * 4 + 0) ^ swa] = v0;
        dst[(ah * 4 + 1) ^ swa] = v1;
        dst[(ah * 4 + 2) ^ swa] = v2;
        dst[(ah * 4 + 3) ^ swa] = v3;
        const uint4* ws = (const uint4*)(Wt + (size_t)wrow * 64);
        uint4* wdst = Ws[0] + wrow * 8;
        wdst[wq ^ sww] = ws[wq];
        wdst[(wq + 4) ^ sww] = ws[wq + 4];
    }
    int gi_next = rowok ? nbr[(size_t)n + rb + arow] : -1;
    int cur = 0;

    for (int k = 0; k < 27; ++k) {
        uint4 a0, a1, a2, a3, w0, w1;
        if (k < 26) {
            a0 = a1 = a2 = a3 = (uint4){0, 0, 0, 0};
            if (gi_next >= 0) {
                const uint4* src = (const uint4*)(fin + (size_t)gi_next * 64) + ah * 4;
                a0 = src[0]; a1 = src[1]; a2 = src[2]; a3 = src[3];
            }
            const uint4* ws = (const uint4*)(Wt + (size_t)(k + 1) * 4096 + (size_t)wrow * 64);
            w0 = ws[wq];
            w1 = ws[wq + 4];
            if (k < 25) gi_next = rowok ? nbr[(size_t)(k + 2) * n + rb + arow] : -1;
        }
        __syncthreads();
        mfma_tile(As[cur], Ws[cur], rowA0, rowA1, swA0, swA1, l15, lg, acc);
        if (k < 26) {
            uint4* dst = As[cur ^ 1] + arow * 8;
            dst[(ah * 4 + 0) ^ swa] = a0;
            dst[(ah * 4 + 1) ^ swa] = a1;
            dst[(ah * 4 + 2) ^ swa] = a2;
            dst[(ah * 4 + 3) ^ swa] = a3;
            uint4* wdst = Ws[cur ^ 1] + wrow * 8;
            wdst[wq ^ sww] = w0;
            wdst[(wq + 4) ^ sww] = w1;
            cur ^= 1;
        }
    }
    int base = rb + w * 32;
#pragma unroll
    for (int rf = 0; rf < 2; ++rf)
#pragma unroll
        for (int nf = 0; nf < 4; ++nf)
#pragma unroll
            for (int q = 0; q < 4; ++q) {
                int r = base + rf * 16 + lg * 4 + q;
                if (r < n) vout[(size_t)r * 64 + nf * 16 + l15] = f2bf(acc[rf][nf][q]);
            }
    __syncthreads();
    float* sp = (float*)As[0];
    int gidx = w * 4 + lg;
#pragma unroll
    for (int nf = 0; nf < 4; ++nf) {
        int col = nf * 16 + l15;
        float s = 0.f, s2 = 0.f;
#pragma unroll
        for (int rf = 0; rf < 2; ++rf)
#pragma unroll
            for (int q = 0; q < 4; ++q) {
                int r = base + rf * 16 + lg * 4 + q;
                if (r < n) {
                    float v = acc[rf][nf][q];
                    s += v;
                    s2 += v * v;
                }
            }
        sp[gidx * 64 + col] = s;
        sp[1024 + gidx * 64 + col] = s2;
    }
    __syncthreads();
    if (t < 64) {
        float s = 0.f, s2 = 0.f;
#pragma unroll
        for (int i = 0; i < 16; ++i) {
            s += sp[i * 64 + t];
            s2 += sp[1024 + i * 64 + t];
        }
        atomicAdd(&stats_out[t], (double)s);
        atomicAdd(&stats_out[64 + t], (double)s2);
    }
}

// ---------------- f16 = bf16(lrelu(bn(t3)) + feat) ----------------
__global__ __launch_bounds__(256) void addfeat_kernel(const ushort* __restrict__ t3, const double* __restrict__ stats,
                                                      const float* __restrict__ g, const float* __restrict__ b,
                                                      const float* __restrict__ feat, ushort* __restrict__ f16,
                                                      int n) {
    __shared__ float sb[128];
    bn_sb(stats, g, b, n, sb);
    long total4 = (long)n * 16;
    for (long i = (long)blockIdx.x * 256 + threadIdx.x; i < total4; i += (long)gridDim.x * 256) {
        int c0 = (int)(i & 15) * 4;
        ushort4 xv = ((const ushort4*)t3)[i];
        float4 fz = ((const float4*)feat)[i];
        ushort4 u;
        u.x = f2bf(lrelu(bf2f(xv.x) * sb[c0 + 0] + sb[64 + c0 + 0]) + fz.x);
        u.y = f2bf(lrelu(bf2f(xv.y) * sb[c0 + 1] + sb[64 + c0 + 1]) + fz.y);
        u.z = f2bf(lrelu(bf2f(xv.z) * sb[c0 + 2] + sb[64 + c0 + 2]) + fz.z);
        u.w = f2bf(lrelu(bf2f(xv.w) * sb[c0 + 3] + sb[64 + c0 + 3]) + fz.w);
        ((ushort4*)f16)[i] = u;
    }
}

// ---------------- o16 = bf16(lrelu(bn(v16))) ----------------
__global__ __launch_bounds__(256) void bnlrelu_tobf16_kernel(const ushort* __restrict__ v,
                                                             const double* __restrict__ stats,
                                                             const float* __restrict__ g, const float* __restrict__ b,
                                                             ushort* __restrict__ o16, int n) {
    __shared__ float sb[128];
    bn_sb(stats, g, b, n, sb);
    long total4 = (long)n * 16;
    for (long i = (long)blockIdx.x * 256 + threadIdx.x; i < total4; i += (long)gridDim.x * 256) {
        int c0 = (int)(i & 15) * 4;
        ushort4 xv = ((const ushort4*)v)[i];
        ushort4 u;
        u.x = f2bf(lrelu(bf2f(xv.x) * sb[c0 + 0] + sb[64 + c0 + 0]));
        u.y = f2bf(lrelu(bf2f(xv.y) * sb[c0 + 1] + sb[64 + c0 + 1]));
        u.z = f2bf(lrelu(bf2f(xv.z) * sb[c0 + 2] + sb[64 + c0 + 2]));
        u.w = f2bf(lrelu(bf2f(xv.w) * sb[c0 + 3] + sb[64 + c0 + 3]));
        ((ushort4*)o16)[i] = u;
    }
}

// ---------------- out = lrelu(bn(w16) + f16) ----------------
__global__ __launch_bounds__(256) void final_kernel(const ushort* __restrict__ w16, const double* __restrict__ stats,
                                                    const float* __restrict__ g, const float* __restrict__ b,
                                                    const ushort* __restrict__ f16, float* __restrict__ out, int n) {
    __shared__ float sb[128];
    bn_sb(stats, g, b, n, sb);
    long total4 = (long)n * 16;
    for (long i = (long)blockIdx.x * 256 + threadIdx.x; i < total4; i += (long)gridDim.x * 256) {
        int c0 = (int)(i & 15) * 4;
        ushort4 xv = ((const ushort4*)w16)[i];
        ushort4 u = ((const ushort4*)f16)[i];
        float4 y;
        y.x = lrelu(bf2f(xv.x) * sb[c0 + 0] + sb[64 + c0 + 0] + bf2f(u.x));
        y.y = lrelu(bf2f(xv.y) * sb[c0 + 1] + sb[64 + c0 + 1] + bf2f(u.y));
        y.z = lrelu(bf2f(xv.z) * sb[c0 + 2] + sb[64 + c0 + 2] + bf2f(u.z));
        y.w = lrelu(bf2f(xv.w) * sb[c0 + 3] + sb[64 + c0 + 3] + bf2f(u.w));
        ((float4*)out)[i] = y;
    }
}

extern "C" void kernel_launch(void* const* d_in, const int* in_sizes, int n_in,
                              void* d_out, int out_size, void* d_ws, size_t ws_size,
                              hipStream_t stream) {
    const float* feat = (const float*)d_in[0];
    const float* lw_W = (const float*)d_in[1];
    const float* lw_g = (const float*)d_in[2];
    const float* lw_b = (const float*)d_in[3];
    const float* w_W = (const float*)d_in[4];
    const float* proj_W = (const float*)d_in[5];
    const float* proj_g = (const float*)d_in[6];
    const float* proj_b = (const float*)d_in[7];
    const float* adaptive_W = (const float*)d_in[8];
    const float* fuse_W = (const float*)d_in[9];
    const float* fuse_g = (const float*)d_in[10];
    const float* fuse_b = (const float*)d_in[11];
    const float* conv1_W = (const float*)d_in[12];
    const float* bn1_g = (const float*)d_in[13];
    const float* bn1_b = (const float*)d_in[14];
    const float* conv2_W = (const float*)d_in[15];
    const float* bn2_g = (const float*)d_in[16];
    const float* bn2_b = (const float*)d_in[17];
    const int* clusters = (const int*)d_in[18];
    const int* nbr = (const int*)d_in[19];

    const int n = in_sizes[0] / 64;

    char* ws = (char*)d_ws;
    size_t off = 0;
    auto alloc = [&](size_t bytes) -> size_t {
        size_t o = off;
        off = (off + bytes + 255) & ~(size_t)255;
        return o;
    };
    // zeroed region
    size_t cnt_off = alloc((size_t)3 * KCL * 4);
    size_t stats_off = alloc((size_t)10 * 128 * 8);
    size_t gmax_off = alloc(16);
    size_t zbytes = off;
    // non-zeroed
    size_t offs_off = alloc((size_t)3 * KCL * 4);
    size_t cur_off = alloc((size_t)3 * KCL * 4);
    size_t perm_off = alloc((size_t)3 * n * 4);
    size_t mean_off = alloc((size_t)3 * KCL * 64 * 4);
    size_t mw_off = alloc((size_t)3 * KCL * 64 * 4);
    size_t seg3_off = alloc((size_t)3 * KCL * 64 * 4);
    size_t adp_off = alloc((size_t)n * 3 * 4);
    size_t feat16_off = alloc((size_t)n * 64 * 2);
    size_t ra_off = alloc((size_t)3 * n * 64 * 2);   // A0..A2; later Ebuf/c2out, c1out, cbuf
    size_t rc_off = alloc((size_t)3 * n * 64 * 2);   // C0..C2; later P3, t3, fbuf16
    size_t wt64_off = alloc((size_t)64 * 4096 * 2);
    size_t wfT_off = alloc((size_t)8192 * 2);

    int* cnts = (int*)(ws + cnt_off);
    double* stats = (double*)(ws + stats_off);
    unsigned* gmax = (unsigned*)(ws + gmax_off);
    int* offs = (int*)(ws + offs_off);
    int* cursor = (int*)(ws + cur_off);
    int* perm = (int*)(ws + perm_off);
    float* meanB3 = (float*)(ws + mean_off);
    float* MW3 = (float*)(ws + mw_off);
    float* seg3 = (float*)(ws + seg3_off);
    float* adp = (float*)(ws + adp_off);
    ushort* feat16 = (ushort*)(ws + feat16_off);
    ushort* RA = (ushort*)(ws + ra_off);
    ushort* RC = (ushort*)(ws + rc_off);
    ushort* wt64 = (ushort*)(ws + wt64_off);
    ushort* wfT = (ushort*)(ws + wfT_off);
    float* outp = (float*)d_out;

    // aliases (liveness-checked)
    ushort* A3 = RA;
    ushort* Ebuf = RA;                               // reused after cgemm3 (A dead)
    ushort* c1out = RA + (size_t)n * 64;             // after cgemm3
    ushort* cbuf = RA + (size_t)2 * n * 64;
    ushort* c2out = RA;                              // after expf loop (Ebuf dead)
    ushort* C3 = RC;
    ushort* P3buf = RC;                              // after all expf (C0 dead)
    ushort* t3buf = RC + (size_t)n * 64;             // after expf (C1 dead)
    ushort* fbuf16 = RC + (size_t)2 * n * 64;        // after expf (C2 dead)

    const ushort* lwW16 = wt64;
    const ushort* wW16 = wt64 + (size_t)3 * 4096;
    const ushort* projW16 = wt64 + (size_t)6 * 4096;
    const ushort* conv1W16 = wt64 + (size_t)10 * 4096;
    const ushort* conv2W16 = wt64 + (size_t)37 * 4096;

    hipMemsetAsync(d_ws, 0, zbytes, stream);

    const int GEMM_BLK = (n + 127) / 128;
    const int EW_BLK = 2048;

    prep_wt64<<<64, 256, 0, stream>>>(lw_W, w_W, proj_W, conv1_W, conv2_W, wt64);
    prep_fuse<<<1, 256, 0, stream>>>(fuse_W, wfT);
    cvt_bf16_kernel<<<EW_BLK, 256, 0, stream>>>(feat, feat16, (long)n * 16);
    adp_kernel<<<1024, 256, 0, stream>>>(feat16, adaptive_W, adp, n);

    hist3_kernel<<<384, 256, 0, stream>>>(clusters, cnts, n);
    scan_kernel<<<3, 256, 0, stream>>>(cnts, offs, cursor, n);
    scatter_kernel<<<1024, 256, 0, stream>>>(clusters, cursor, perm, n);

    // A_j = feat16 @ lw_j (3 outputs, bf16) + stats(0,2,4)
    lw3_gemm<<<GEMM_BLK, 256, 0, stream>>>(feat16, lwW16, A3, n, stats);
    // meanB for all levels
    reduce_mean3_kernel<<<3 * KCL, 256, 0, stream>>>(A3, stats, lw_g, lw_b, n, cnts, offs, perm, meanB3);
    // MW_l = meanB_l @ wW_l
    mw3_gemm<<<3 * 16, 256, 0, stream>>>(meanB3, wW16, MW3);
    // C_l = bnlrelu(A_l) @ wW_l - MW_l[clus], bf16 + gmax_l
    cgemm3<<<3 * GEMM_BLK, 256, 0, stream>>>(A3, wW16, MW3, clusters, stats, lw_g, lw_b, C3, gmax, n, GEMM_BLK);

    for (int i = 0; i < 3; ++i) {
        // E = feat16 @ proj_i, bf16 + stats(2i+1)
        gemm_stats_bf16out<<<GEMM_BLK, 256, 0, stream>>>(feat16, projW16 + (size_t)i * 4096, Ebuf, n,
                                                         stats + (size_t)(2 * i + 1) * 128);
        // seg3_i[c] = Σ lrelu(bn(E))·exp(C-gmax) / (Σ exp(C-gmax) + 1e-6)
        reduce_expf_kernel<<<KCL, 256, 0, stream>>>(C3 + (size_t)i * n * 64, Ebuf,
                                                    stats + (size_t)(2 * i + 1) * 128,
                                                    proj_g + i * 64, proj_b + i * 64, n, gmax + i,
                                                    cnts + (size_t)i * KCL, offs + (size_t)i * KCL, perm,
                                                    seg3 + (size_t)i * KCL * 64);
    }

    // P3 = feat16 @ proj_3, bf16 + stats(6)
    gemm_stats_bf16out<<<GEMM_BLK, 256, 0, stream>>>(feat16, projW16 + (size_t)3 * 4096, P3buf, n,
                                                     stats + (size_t)6 * 128);
    // t3 = [bnlrelu(P3) | blend] @ fuse_W, bf16 + stats(7)
    fuse_mfma<<<GEMM_BLK, 256, 0, stream>>>(P3buf, stats + 6 * 128, proj_g + 192, proj_b + 192, n,
                                            adp, clusters,
                                            seg3, seg3 + (size_t)KCL * 64, seg3 + (size_t)2 * KCL * 64,
                                            wfT, t3buf, stats + 7 * 128);
    // f = lrelu(bn(t3)) + feat  (bf16)
    addfeat_kernel<<<EW_BLK, 256, 0, stream>>>(t3buf, stats + 7 * 128, fuse_g, fuse_b, feat, fbuf16, n);

    // conv1 -> c1out bf16 + stats(8); bn1+lrelu -> cbuf
    subm_conv_db<<<GEMM_BLK, 256, 0, stream>>>(fbuf16, nbr, conv1W16, c1out, n, stats + 8 * 128);
    bnlrelu_tobf16_kernel<<<EW_BLK, 256, 0, stream>>>(c1out, stats + 8 * 128, bn1_g, bn1_b, cbuf, n);

    // conv2 -> c2out bf16 + stats(9); out = lrelu(bn2 + f)
    subm_conv_db<<<GEMM_BLK, 256, 0, stream>>>(cbuf, nbr, conv2W16, c2out, n, stats + 9 * 128);
    final_kernel<<<EW_BLK, 256, 0, stream>>>(c2out, stats + 9 * 128, bn2_g, bn2_b, fbuf16, outp, n);
}